// Round 7
// baseline (434.933 us; speedup 1.0000x reference)
//
#include <hip/hip_runtime.h>
#include <stdint.h>

#define N_NODES 40000
#define N_EDGES 1280000
#define HPAD 16               // one hist counter per 64B line

// k1 block-role layout: 1250 atomic blocks striped 1:2 with 2855 streaming blocks
#define K1_GRID 4105          // 1250 hist + 157 coord4 + 80 wpack + 2618 zero
#define NB5 625               // k5: 64-node tiles
#define COORD_BLOCKS 469      // ceil(40000*3/256)

typedef __attribute__((ext_vector_type(8))) short bf16x8;   // 8 bf16 in 4 VGPRs
typedef __attribute__((ext_vector_type(4))) float f32x4;    // MFMA C/D

#define MFMA16(a, b, c) __builtin_amdgcn_mfma_f32_16x16x32_bf16((a), (b), (c), 0, 0, 0)

#if defined(__has_builtin)
#if __has_builtin(__builtin_amdgcn_cvt_pk_bf16_f32)
#define HAS_CVT_PK_BF16 1
#endif
#endif

// ---------- helpers ----------
__device__ __forceinline__ float fast_silu(float x) {
    float e = __expf(-x);
    return x * __builtin_amdgcn_rcpf(1.0f + e);
}

__device__ __forceinline__ unsigned short f2bf(float x) {
    unsigned int u = __float_as_uint(x);
    u = (u + 0x7FFFu + ((u >> 16) & 1u)) >> 16;
    return (unsigned short)u;
}

__device__ __forceinline__ unsigned int pack_bf2(float a, float b) {
#ifdef HAS_CVT_PK_BF16
    typedef __attribute__((ext_vector_type(2))) __bf16 bf2_t;
    bf2_t r = __builtin_amdgcn_cvt_pk_bf16_f32(a, b);   // low = a, high = b, RNE
    return __builtin_bit_cast(unsigned int, r);
#else
    unsigned int ua = __float_as_uint(a);
    unsigned int ub = __float_as_uint(b);
    ua = (ua + 0x7FFFu + ((ua >> 16) & 1u)) >> 16;
    ub = (ub + 0x7FFFu + ((ub >> 16) & 1u)) & 0xFFFF0000u;
    return (ua & 0xFFFFu) | ub;
#endif
}

__device__ __forceinline__ float bf16_to_f(unsigned short s) {
    return __uint_as_float(((unsigned int)s) << 16);
}

// ============================================================================
// k1: hist (padded counters) + u16 rank, striped 1:2 with independent
//     streaming work.
// ============================================================================
__global__ void hist_rank_kernel(const int* __restrict__ eidx, const float* __restrict__ coord,
                                 const float* __restrict__ We2,
                                 const float* __restrict__ Wc1, const float* __restrict__ Wn1,
                                 const float* __restrict__ Wn2,
                                 int* __restrict__ histp, unsigned short* __restrict__ rank,
                                 float4* __restrict__ coord4,
                                 unsigned short* __restrict__ Wt2,
                                 unsigned short* __restrict__ Wtc1, unsigned short* __restrict__ Wtn1,
                                 unsigned short* __restrict__ Wtn2,
                                 float* __restrict__ aggz)
{
    const int g = blockIdx.x;
    if (g < 3750 && (g % 3) == 0) {
        const int i = ((g / 3) * 256 + threadIdx.x) * 4;
        const int4 r = *(const int4*)(eidx + i);
        const int kx = atomicAdd(&histp[r.x * HPAD], 1);
        const int ky = atomicAdd(&histp[r.y * HPAD], 1);
        const int kz = atomicAdd(&histp[r.z * HPAD], 1);
        const int kw = atomicAdd(&histp[r.w * HPAD], 1);
        *(ushort4*)(rank + i) = make_ushort4((unsigned short)kx, (unsigned short)ky,
                                             (unsigned short)kz, (unsigned short)kw);
        return;
    }
    const int s = (g < 3750) ? (g - g / 3 - 1) : (g - 1250);
    if (s < 157) {
        const int n = s * 256 + threadIdx.x;
        if (n < N_NODES)
            coord4[n] = make_float4(coord[n * 3 + 0], coord[n * 3 + 1], coord[n * 3 + 2], 0.f);
    } else if (s < 237) {
        const int t = (s - 157) * 256 + threadIdx.x;
        if (t < 4096)       { Wt2[t]  = f2bf(We2[(t & 63) * 64 + (t >> 6)]); }
        else if (t < 8192)  { int u = t - 4096;  Wtc1[u] = f2bf(Wc1[(u & 63) * 64 + (u >> 6)]); }
        else if (t < 16384) { int u = t - 8192;  Wtn1[u] = f2bf(Wn1[(u & 127) * 64 + (u >> 7)]); }
        else if (t < 20480) { int u = t - 16384; Wtn2[u] = f2bf(Wn2[(u & 63) * 64 + (u >> 6)]); }
    } else {
        const int i = ((s - 237) * 256 + threadIdx.x) * 4;
        if (i < N_NODES * 67)
            *(float4*)(aggz + i) = make_float4(0.f, 0.f, 0.f, 0.f);
    }
}

// ============================================================================
// k2a: compact padded hist -> cnt  PLUS  P-GEMM (P[n] = h[n]@We1 halves, f32)
// ============================================================================
__global__ __launch_bounds__(256) void compact_pgemm_kernel(
    const int* __restrict__ histp, int* __restrict__ cnt,
    const float* __restrict__ h, const float* __restrict__ We1,
    float* __restrict__ P)
{
    const int b = blockIdx.x;
    if (b < 157) {
        const int n = b * 256 + threadIdx.x;
        if (n < N_NODES) cnt[n] = histp[n * HPAD];
        return;
    }
    __shared__ __align__(16) unsigned short Hs[64 * 72];
    __shared__ __align__(16) unsigned short Wa[64 * 72];
    __shared__ __align__(16) unsigned short Wb[64 * 72];
    const int t = threadIdx.x;
    const int nbase = (b - 157) * 64;

    {
        const int nl = t >> 2, seg = t & 3;
        const float* hp = h + (size_t)(nbase + nl) * 64 + seg * 16;
        const float4 v0 = *(const float4*)(hp + 0);
        const float4 v1 = *(const float4*)(hp + 4);
        const float4 v2 = *(const float4*)(hp + 8);
        const float4 v3 = *(const float4*)(hp + 12);
        uint4 a, c;
        a.x = pack_bf2(v0.x, v0.y); a.y = pack_bf2(v0.z, v0.w);
        a.z = pack_bf2(v1.x, v1.y); a.w = pack_bf2(v1.z, v1.w);
        c.x = pack_bf2(v2.x, v2.y); c.y = pack_bf2(v2.z, v2.w);
        c.z = pack_bf2(v3.x, v3.y); c.w = pack_bf2(v3.z, v3.w);
        *(uint4*)&Hs[nl * 72 + seg * 16 + 0] = a;
        *(uint4*)&Hs[nl * 72 + seg * 16 + 8] = c;
    }
    {
        const int out = t >> 2, seg = t & 3;
        unsigned short wa[16], wb[16];
        #pragma unroll
        for (int j = 0; j < 16; ++j) {
            const int k = seg * 16 + j;
            wa[j] = f2bf(We1[k * 64 + out]);
            wb[j] = f2bf(We1[(64 + k) * 64 + out]);
        }
        *(uint4*)&Wa[out * 72 + seg * 16 + 0] = *(const uint4*)&wa[0];
        *(uint4*)&Wa[out * 72 + seg * 16 + 8] = *(const uint4*)&wa[8];
        *(uint4*)&Wb[out * 72 + seg * 16 + 0] = *(const uint4*)&wb[0];
        *(uint4*)&Wb[out * 72 + seg * 16 + 8] = *(const uint4*)&wb[8];
    }
    __syncthreads();

    const int wave = t >> 6, L = t & 63;
    const int q = L >> 4, lc = L & 15;
    const int wbase = wave * 16;

    f32x4 acc[4][2];
    #pragma unroll
    for (int ot = 0; ot < 4; ++ot)
        #pragma unroll
        for (int hf = 0; hf < 2; ++hf)
            #pragma unroll
            for (int i = 0; i < 4; ++i) acc[ot][hf][i] = 0.0f;

    #pragma unroll
    for (int ks = 0; ks < 2; ++ks) {
        const bf16x8 bfr = *(const bf16x8*)&Hs[(wbase + lc) * 72 + ks * 32 + q * 8];
        #pragma unroll
        for (int ot = 0; ot < 4; ++ot) {
            const bf16x8 afa = *(const bf16x8*)&Wa[(ot * 16 + lc) * 72 + ks * 32 + q * 8];
            acc[ot][0] = MFMA16(afa, bfr, acc[ot][0]);
            const bf16x8 afb = *(const bf16x8*)&Wb[(ot * 16 + lc) * 72 + ks * 32 + q * 8];
            acc[ot][1] = MFMA16(afb, bfr, acc[ot][1]);
        }
    }
    float* pr = P + (size_t)(nbase + wbase + lc) * 128;
    #pragma unroll
    for (int ot = 0; ot < 4; ++ot) {
        *(f32x4*)(pr + ot * 16 + q * 4)      = acc[ot][0];
        *(f32x4*)(pr + 64 + ot * 16 + q * 4) = acc[ot][1];
    }
}

// ============================================================================
// k2b: single-block scan; offs[0..N_NODES] inclusive sentinel
// ============================================================================
__global__ __launch_bounds__(1024) void scan_kernel(const int* __restrict__ cnt,
                                                    int* __restrict__ offs) {
    __shared__ int wtot[16];
    __shared__ int carry_s;
    const int t = threadIdx.x;
    const int wave = t >> 6, lane = t & 63;
    if (t == 0) carry_s = 0;
    __syncthreads();
    for (int base = 0; base < N_NODES; base += 8192) {
        const int idx = base + t * 8;
        int v[8];
        if (idx + 8 <= N_NODES) {
            const int4 a = *(const int4*)(cnt + idx);
            const int4 b = *(const int4*)(cnt + idx + 4);
            v[0] = a.x; v[1] = a.y; v[2] = a.z; v[3] = a.w;
            v[4] = b.x; v[5] = b.y; v[6] = b.z; v[7] = b.w;
        } else {
            #pragma unroll
            for (int j = 0; j < 8; ++j) v[j] = (idx + j < N_NODES) ? cnt[idx + j] : 0;
        }
        int s = 0;
        #pragma unroll
        for (int j = 0; j < 8; ++j) s += v[j];
        int S = s;
        #pragma unroll
        for (int d = 1; d < 64; d <<= 1) {
            const int u = __shfl_up(S, d, 64);
            if (lane >= d) S += u;
        }
        if (lane == 63) wtot[wave] = S;
        __syncthreads();
        if (wave == 0 && lane < 16) {
            int w = wtot[lane];
            #pragma unroll
            for (int d = 1; d < 16; d <<= 1) {
                const int u = __shfl_up(w, d, 64);
                if (lane >= d) w += u;
            }
            wtot[lane] = w;
        }
        __syncthreads();
        const int wb = (wave == 0) ? 0 : wtot[wave - 1];
        int run = carry_s + wb + (S - s);
        #pragma unroll
        for (int j = 0; j < 8; ++j) {
            if (idx + j < N_NODES) offs[idx + j] = run;
            run += v[j];
        }
        __syncthreads();
        if (t == 0) carry_s += wtot[15];
        __syncthreads();
    }
    if (t == 0) offs[N_NODES] = N_EDGES;
}

// ============================================================================
// k3: scatter 8B payloads (rc, mask) via offs[r]+rank[e] (NO atomics) + h pack.
// ============================================================================
__global__ void scatter_prep_kernel(const int* __restrict__ eidx, const float* __restrict__ emask,
                                    const unsigned short* __restrict__ rank,
                                    const int* __restrict__ offs,
                                    uint2* __restrict__ payload,
                                    const float* __restrict__ h,
                                    unsigned short* __restrict__ h_bf)
{
    const int b = blockIdx.x;
    if (b < 1250) {
        const int i = (b * 256 + threadIdx.x) * 4;
        const int4 r = *(const int4*)(eidx + i);
        const int4 c = *(const int4*)(eidx + N_EDGES + i);
        const float4 mk = *(const float4*)(emask + i);
        const ushort4 k = *(const ushort4*)(rank + i);
        #pragma unroll
        for (int j = 0; j < 4; ++j) {
            const int rj = (&r.x)[j], cj = (&c.x)[j];
            const int slot = offs[rj] + (int)(&k.x)[j];
            payload[slot] = make_uint2((unsigned)rj | ((unsigned)cj << 16),
                                       __float_as_uint((&mk.x)[j]));
        }
    } else {
        const int i = ((b - 1250) * 256 + threadIdx.x) * 4;   // exactly covers 2,560,000
        const float4 v = *(const float4*)(h + i);
        *(uint2*)(h_bf + i) = make_uint2(pack_bf2(v.x, v.y), pack_bf2(v.z, v.w));
    }
}

// ============================================================================
// k4: edge kernel — 128-edge blocks for 8 blocks/CU (LDS 20480B exactly).
//     4 waves x 32 edges; each half-wave duplicates the other's metadata.
//     Occupancy 16 -> 32 waves/CU to fill the ~34% idle issue slots.
// ============================================================================
__global__ __launch_bounds__(256, 8) void egcl_edge_mfma(
    const float* __restrict__ P,
    const uint2* __restrict__ payload,
    const int* __restrict__ offs_g,
    const float4* __restrict__ coord4,
    const float* __restrict__ We1, const float* __restrict__ be1,
    const float* __restrict__ be2, const float* __restrict__ bc1,
    const float* __restrict__ Wc2,
    const unsigned short* __restrict__ Wt2,
    const unsigned short* __restrict__ Wtc1,
    float* __restrict__ agg, float* __restrict__ aggc)
{
    __shared__ __align__(16) unsigned short A[128 * 72];   // 18432 B
    __shared__ float dif_s[384];                           //  1536 B
    __shared__ float cval_s[128];                          //   512 B

    const int t = threadIdx.x;
    const int w = t >> 6, L = t & 63;
    const int q = L >> 4, lc = L & 15;
    const int ebase = blockIdx.x * 128;
    const int rbase = w * 32;
    const int el = rbase + (L & 31);      // this lane's edge (lanes 32-63 duplicate 0-31)

    // ---- meta: 8B payload + 2 L2-resident coord4 gathers ----
    int my_r, my_c;
    float my_rad, my_msk;
    {
        const uint2 pl = payload[ebase + el];
        my_r = (int)(pl.x & 0xFFFFu);
        my_c = (int)(pl.x >> 16);
        my_msk = __uint_as_float(pl.y);
        const float4 cr = coord4[my_r];
        const float4 cc = coord4[my_c];
        const float d0 = cr.x - cc.x, d1 = cr.y - cc.y, d2 = cr.z - cc.z;
        my_rad = d0 * d0 + d1 * d1 + d2 * d2;
        if (L < 32) { dif_s[el * 3 + 0] = d0; dif_s[el * 3 + 1] = d1; dif_s[el * 3 + 2] = d2; }
        if (t == 0)   *(int*)&A[64] = my_r;   // n0 (edge 0) in row-0 padding
        if (t == 223) *(int*)&A[66] = my_r;   // n1 (edge 127: wave 3, lane 31)
    }

    // per-et indices / rad / mask via shfl (lane et*16+lc holds edge rbase+et*16+lc)
    int r_et[2], c_et[2];
    float rad_et[2], mk_et[2];
    #pragma unroll
    for (int et = 0; et < 2; ++et) {
        r_et[et]   = __shfl(my_r, et * 16 + lc, 64);
        c_et[et]   = __shfl(my_c, et * 16 + lc, 64);
        rad_et[et] = __shfl(my_rad, et * 16 + lc, 64);
        mk_et[et]  = __shfl(my_msk, et * 16 + lc, 64);
    }

    // ---- layer1 = bias + rad*w + P[row] + P[col] (f32, no MFMA) ----
    f32x4 acc[4][2];   // [ot][et]
    #pragma unroll
    for (int ot = 0; ot < 4; ++ot) {
        const float4 bv = *(const float4*)(be1 + ot * 16 + q * 4);
        const float4 wv = *(const float4*)(We1 + 128 * 64 + ot * 16 + q * 4);
        #pragma unroll
        for (int et = 0; et < 2; ++et) {
            const float rad = rad_et[et];
            acc[ot][et][0] = fmaf(rad, wv.x, bv.x);
            acc[ot][et][1] = fmaf(rad, wv.y, bv.y);
            acc[ot][et][2] = fmaf(rad, wv.z, bv.z);
            acc[ot][et][3] = fmaf(rad, wv.w, bv.w);
        }
    }
    #pragma unroll
    for (int et = 0; et < 2; ++et) {
        const float* p1 = P + (size_t)r_et[et] * 128;
        const float* p2 = P + (size_t)c_et[et] * 128 + 64;
        #pragma unroll
        for (int ot = 0; ot < 4; ++ot) {
            const f32x4 a = *(const f32x4*)(p1 + ot * 16 + q * 4);
            const f32x4 b = *(const f32x4*)(p2 + ot * 16 + q * 4);
            acc[ot][et][0] += a[0] + b[0];
            acc[ot][et][1] += a[1] + b[1];
            acc[ot][et][2] += a[2] + b[2];
            acc[ot][et][3] += a[3] + b[3];
        }
    }

    // ---- m1 = silu -> A ----
    #pragma unroll
    for (int et = 0; et < 2; ++et) {
        const int row = rbase + et * 16 + lc;
        #pragma unroll
        for (int ot = 0; ot < 4; ++ot) {
            uint2 p;
            p.x = pack_bf2(fast_silu(acc[ot][et][0]), fast_silu(acc[ot][et][1]));
            p.y = pack_bf2(fast_silu(acc[ot][et][2]), fast_silu(acc[ot][et][3]));
            *(uint2*)&A[row * 72 + ot * 16 + q * 4] = p;
        }
    }

    // ---- layer2 ----
    f32x4 acc2[4][2];
    #pragma unroll
    for (int ot = 0; ot < 4; ++ot) {
        const float4 bv = *(const float4*)(be2 + ot * 16 + q * 4);
        #pragma unroll
        for (int et = 0; et < 2; ++et) {
            acc2[ot][et][0] = bv.x; acc2[ot][et][1] = bv.y;
            acc2[ot][et][2] = bv.z; acc2[ot][et][3] = bv.w;
        }
    }
    #pragma unroll
    for (int ks = 0; ks < 2; ++ks) {
        bf16x8 bfr[2];
        #pragma unroll
        for (int et = 0; et < 2; ++et)
            bfr[et] = *(const bf16x8*)&A[(rbase + et * 16 + lc) * 72 + ks * 32 + q * 8];
        #pragma unroll
        for (int ot = 0; ot < 4; ++ot) {
            const bf16x8 af = *(const bf16x8*)&Wt2[(ot * 16 + lc) * 64 + ks * 32 + q * 8];
            #pragma unroll
            for (int et = 0; et < 2; ++et)
                acc2[ot][et] = MFMA16(af, bfr[et], acc2[ot][et]);
        }
    }

    // ---- m = silu * mask -> A ----
    #pragma unroll
    for (int et = 0; et < 2; ++et) {
        const int row = rbase + et * 16 + lc;
        const float mk = mk_et[et];
        #pragma unroll
        for (int ot = 0; ot < 4; ++ot) {
            uint2 p;
            p.x = pack_bf2(fast_silu(acc2[ot][et][0]) * mk, fast_silu(acc2[ot][et][1]) * mk);
            p.y = pack_bf2(fast_silu(acc2[ot][et][2]) * mk, fast_silu(acc2[ot][et][3]) * mk);
            *(uint2*)&A[row * 72 + ot * 16 + q * 4] = p;
        }
    }

    // ---- coord mlp ----
    f32x4 acc3[4][2];
    #pragma unroll
    for (int ot = 0; ot < 4; ++ot) {
        const float4 bv = *(const float4*)(bc1 + ot * 16 + q * 4);
        #pragma unroll
        for (int et = 0; et < 2; ++et) {
            acc3[ot][et][0] = bv.x; acc3[ot][et][1] = bv.y;
            acc3[ot][et][2] = bv.z; acc3[ot][et][3] = bv.w;
        }
    }
    #pragma unroll
    for (int ks = 0; ks < 2; ++ks) {
        bf16x8 bfr[2];
        #pragma unroll
        for (int et = 0; et < 2; ++et)
            bfr[et] = *(const bf16x8*)&A[(rbase + et * 16 + lc) * 72 + ks * 32 + q * 8];
        #pragma unroll
        for (int ot = 0; ot < 4; ++ot) {
            const bf16x8 af = *(const bf16x8*)&Wtc1[(ot * 16 + lc) * 64 + ks * 32 + q * 8];
            #pragma unroll
            for (int et = 0; et < 2; ++et)
                acc3[ot][et] = MFMA16(af, bfr[et], acc3[ot][et]);
        }
    }
    {
        float4 wv[4];
        #pragma unroll
        for (int ot = 0; ot < 4; ++ot) wv[ot] = *(const float4*)(Wc2 + ot * 16 + q * 4);
        #pragma unroll
        for (int et = 0; et < 2; ++et) {
            float s = 0.0f;
            #pragma unroll
            for (int ot = 0; ot < 4; ++ot) {
                s = fmaf(fast_silu(acc3[ot][et][0]), wv[ot].x, s);
                s = fmaf(fast_silu(acc3[ot][et][1]), wv[ot].y, s);
                s = fmaf(fast_silu(acc3[ot][et][2]), wv[ot].z, s);
                s = fmaf(fast_silu(acc3[ot][et][3]), wv[ot].w, s);
            }
            s += __shfl_xor(s, 16, 64);
            s += __shfl_xor(s, 32, 64);
            if (q == 0)
                cval_s[rbase + et * 16 + lc] = s * mk_et[et];
        }
    }

    __syncthreads();   // whole block's m / cval / dif now valid

    // ---- fused segmented aggregation (128-slot window) ----
    {
        const int n0 = *(const int*)&A[64];
        const int n1 = *(const int*)&A[66];
        const int half = L >> 5;          // 0: even slots, 1: odd slots
        const int cp = L & 31;            // column pair (cols 2cp, 2cp+1)
        const bool c3 = (cp < 3);
        for (int n = n0 + w; n <= n1; n += 4) {
            const int os = offs_g[n];
            const int oe = offs_g[n + 1];
            const int s0 = max(os - ebase, 0);
            const int s1 = min(oe - ebase, 128);
            float sx = 0.0f, sy = 0.0f, t3 = 0.0f;
            int slot = s0 + half;
            for (; slot + 2 < s1; slot += 4) {
                const unsigned ua = *(const unsigned*)&A[(slot + 0) * 72 + cp * 2];
                const unsigned ub = *(const unsigned*)&A[(slot + 2) * 72 + cp * 2];
                sx += __uint_as_float(ua << 16) + __uint_as_float(ub << 16);
                sy += __uint_as_float(ua & 0xFFFF0000u) + __uint_as_float(ub & 0xFFFF0000u);
                if (c3) {
                    t3 = fmaf(dif_s[(slot + 0) * 3 + cp], cval_s[slot + 0], t3);
                    t3 = fmaf(dif_s[(slot + 2) * 3 + cp], cval_s[slot + 2], t3);
                }
            }
            if (slot < s1) {
                const unsigned ua = *(const unsigned*)&A[slot * 72 + cp * 2];
                sx += __uint_as_float(ua << 16);
                sy += __uint_as_float(ua & 0xFFFF0000u);
                if (c3) t3 = fmaf(dif_s[slot * 3 + cp], cval_s[slot], t3);
            }
            sx += __shfl_xor(sx, 32, 64);
            sy += __shfl_xor(sy, 32, 64);
            if (c3) t3 += __shfl_xor(t3, 32, 64);
            const bool interior = (os >= ebase) && (oe <= ebase + 128);
            if (half == 0) {
                if (interior) {
                    float2 v; v.x = sx; v.y = sy;
                    *(float2*)&agg[(size_t)n * 64 + cp * 2] = v;
                    if (c3) aggc[n * 3 + cp] = t3;
                } else {
                    atomicAdd(&agg[(size_t)n * 64 + cp * 2 + 0], sx);
                    atomicAdd(&agg[(size_t)n * 64 + cp * 2 + 1], sy);
                    if (c3) atomicAdd(&aggc[n * 3 + cp], t3);
                }
            }
        }
    }
}

// ============================================================================
// k5: node MLP + coord output — 64-node tiles; degree from offs diff
// ============================================================================
__global__ __launch_bounds__(256, 8) void egcl_node_coord(
    const unsigned short* __restrict__ h_bf, const float* __restrict__ agg,
    const float* __restrict__ bn1, const float* __restrict__ bn2,
    const unsigned short* __restrict__ Wtn1, const unsigned short* __restrict__ Wtn2,
    const float* __restrict__ coord, const float* __restrict__ aggc,
    const int* __restrict__ offs,
    float* __restrict__ hout, float* __restrict__ cout)
{
    if (blockIdx.x >= NB5) {
        const int i = (blockIdx.x - NB5) * 256 + threadIdx.x;
        if (i < N_NODES * 3) {
            const int node = i / 3;
            const float c = fmaxf((float)(offs[node + 1] - offs[node]), 1.0f);
            cout[i] = coord[i] + aggc[i] * __builtin_amdgcn_rcpf(c);
        }
        return;
    }

    __shared__ __align__(16) unsigned short A[64 * 136];
    const int t = threadIdx.x;
    const int wave = t >> 6, L = t & 63;
    const int q = L >> 4, lc = L & 15;
    const int nbase = blockIdx.x * 64;
    const int rbase = wave * 16;

    #pragma unroll
    for (int it = 0; it < 8; ++it) {
        const int idx = it * 256 + t;         // 0..2047 = 64 rows x 32 parts
        const int ln = idx >> 5, part = idx & 31;
        const int node = nbase + ln;
        uint2 u;
        if (part < 16) {
            u = *(const uint2*)(h_bf + (size_t)node * 64 + part * 4);
        } else {
            const float4 v = *(const float4*)(agg + (size_t)node * 64 + (part - 16) * 4);
            u = make_uint2(pack_bf2(v.x, v.y), pack_bf2(v.z, v.w));
        }
        *(uint2*)&A[ln * 136 + part * 4] = u;
    }
    __syncthreads();

    f32x4 acc1[4];
    #pragma unroll
    for (int ct = 0; ct < 4; ++ct) {
        const float b = bn1[ct * 16 + lc];
        #pragma unroll
        for (int i = 0; i < 4; ++i) acc1[ct][i] = b;
    }
    #pragma unroll
    for (int ks = 0; ks < 4; ++ks) {
        const bf16x8 af = *(const bf16x8*)&A[(rbase + lc) * 136 + ks * 32 + q * 8];
        #pragma unroll
        for (int ct = 0; ct < 4; ++ct) {
            const bf16x8 bf = *(const bf16x8*)&Wtn1[(ct * 16 + lc) * 128 + ks * 32 + q * 8];
            acc1[ct] = MFMA16(af, bf, acc1[ct]);
        }
    }
    __syncthreads();

    #pragma unroll
    for (int ct = 0; ct < 4; ++ct)
        #pragma unroll
        for (int i = 0; i < 4; ++i) {
            const int row = rbase + q * 4 + i;
            A[row * 72 + ct * 16 + lc] = f2bf(fast_silu(acc1[ct][i]));
        }
    __syncthreads();

    f32x4 acc2[4];
    #pragma unroll
    for (int ct = 0; ct < 4; ++ct) {
        const float b = bn2[ct * 16 + lc];
        #pragma unroll
        for (int i = 0; i < 4; ++i) acc2[ct][i] = b;
    }
    #pragma unroll
    for (int ks = 0; ks < 2; ++ks) {
        const bf16x8 af = *(const bf16x8*)&A[(rbase + lc) * 72 + ks * 32 + q * 8];
        #pragma unroll
        for (int ct = 0; ct < 4; ++ct) {
            const bf16x8 bf = *(const bf16x8*)&Wtn2[(ct * 16 + lc) * 64 + ks * 32 + q * 8];
            acc2[ct] = MFMA16(af, bf, acc2[ct]);
        }
    }

    #pragma unroll
    for (int ct = 0; ct < 4; ++ct)
        #pragma unroll
        for (int i = 0; i < 4; ++i) {
            const int node = nbase + rbase + q * 4 + i;
            hout[(size_t)node * 64 + ct * 16 + lc] = acc2[ct][i];
        }
}

// ============================================================================
// launch
// ============================================================================
extern "C" void kernel_launch(void* const* d_in, const int* in_sizes, int n_in,
                              void* d_out, int out_size, void* d_ws, size_t ws_size,
                              hipStream_t stream)
{
    const float* h     = (const float*)d_in[0];
    const float* coord = (const float*)d_in[1];
    const int*   eidx  = (const int*)d_in[2];
    const float* emask = (const float*)d_in[3];
    const float* We1   = (const float*)d_in[4];
    const float* be1   = (const float*)d_in[5];
    const float* We2   = (const float*)d_in[6];
    const float* be2   = (const float*)d_in[7];
    const float* Wn1   = (const float*)d_in[8];
    const float* bn1   = (const float*)d_in[9];
    const float* Wn2   = (const float*)d_in[10];
    const float* bn2   = (const float*)d_in[11];
    const float* Wc1   = (const float*)d_in[12];
    const float* bc1   = (const float*)d_in[13];
    const float* Wc2   = (const float*)d_in[14];

    float* hout = (float*)d_out;
    float* cout = hout + (size_t)N_NODES * 64;

    // ws layout (all chunks 16B-multiples)
    char* p = (char*)d_ws;
    float* agg  = (float*)p;                      p += (size_t)N_NODES * 64 * 4;   // 10.24 MB
    float* aggc = (float*)p;                      p += (size_t)N_NODES * 3 * 4;    // 0.48 MB (contiguous with agg for zeroing)
    int* histp  = (int*)p;                        p += (size_t)N_NODES * HPAD * 4; // 2.56 MB padded hist
    int* offs   = (int*)p;                        p += (size_t)(N_NODES + 4) * 4;  // 40001 used
    int* cnt    = (int*)p;                        p += (size_t)N_NODES * 4;        // 0.16 MB
    unsigned short* rank = (unsigned short*)p;    p += (size_t)N_EDGES * 2;        // 2.56 MB (u16)
    uint2* payload = (uint2*)p;                   p += (size_t)N_EDGES * 8;        // 10.24 MB
    unsigned short* h_bf = (unsigned short*)p;    p += (size_t)N_NODES * 64 * 2;   // 5.12 MB
    float4* coord4 = (float4*)p;                  p += (size_t)N_NODES * 16;       // 0.64 MB
    float* P = (float*)p;                         p += (size_t)N_NODES * 128 * 4;  // 20.48 MB node projections
    unsigned short* Wt2  = (unsigned short*)p;    p += 4096 * 2;
    unsigned short* Wtc1 = (unsigned short*)p;    p += 4096 * 2;
    unsigned short* Wtn1 = (unsigned short*)p;    p += 8192 * 2;
    unsigned short* Wtn2 = (unsigned short*)p;    p += 4096 * 2;

    hipMemsetAsync(histp, 0, (size_t)N_NODES * HPAD * 4, stream);   // 2.56 MB
    hist_rank_kernel<<<K1_GRID, 256, 0, stream>>>(eidx, coord, We2, Wc1, Wn1, Wn2,
                                                  histp, rank, coord4,
                                                  Wt2, Wtc1, Wtn1, Wtn2, agg);
    compact_pgemm_kernel<<<782, 256, 0, stream>>>(histp, cnt, h, We1, P);
    scan_kernel<<<1, 1024, 0, stream>>>(cnt, offs);
    scatter_prep_kernel<<<3750, 256, 0, stream>>>(eidx, emask, rank, offs, payload, h, h_bf);
    egcl_edge_mfma<<<N_EDGES / 128, 256, 0, stream>>>(
        P, payload, offs, coord4,
        We1, be1, be2, bc1, Wc2, Wt2, Wtc1, agg, aggc);
    egcl_node_coord<<<NB5 + COORD_BLOCKS, 256, 0, stream>>>(
        h_bf, agg, bn1, bn2, Wtn1, Wtn2, coord, aggc, offs, hout, cout);
}

// Round 8
// 360.345 us; speedup vs baseline: 1.2070x; 1.2070x over previous
//
#include <hip/hip_runtime.h>
#include <stdint.h>

#define N_NODES 40000
#define N_EDGES 1280000
#define HPAD 16               // one hist counter per 64B line

// k1 block-role layout: 1250 atomic blocks striped 1:2 with 2855 streaming blocks
#define K1_GRID 4105          // 1250 hist + 157 coord4 + 80 wpack + 2618 zero
#define NB5 625               // k5: 64-node tiles
#define COORD_BLOCKS 469      // ceil(40000*3/256)

typedef __attribute__((ext_vector_type(8))) short bf16x8;   // 8 bf16 in 4 VGPRs
typedef __attribute__((ext_vector_type(4))) float f32x4;    // MFMA C/D

#define MFMA16(a, b, c) __builtin_amdgcn_mfma_f32_16x16x32_bf16((a), (b), (c), 0, 0, 0)

#if defined(__has_builtin)
#if __has_builtin(__builtin_amdgcn_cvt_pk_bf16_f32)
#define HAS_CVT_PK_BF16 1
#endif
#endif

// ---------- helpers ----------
__device__ __forceinline__ float fast_silu(float x) {
    float e = __expf(-x);
    return x * __builtin_amdgcn_rcpf(1.0f + e);
}

__device__ __forceinline__ unsigned short f2bf(float x) {
    unsigned int u = __float_as_uint(x);
    u = (u + 0x7FFFu + ((u >> 16) & 1u)) >> 16;
    return (unsigned short)u;
}

__device__ __forceinline__ unsigned int pack_bf2(float a, float b) {
#ifdef HAS_CVT_PK_BF16
    typedef __attribute__((ext_vector_type(2))) __bf16 bf2_t;
    bf2_t r = __builtin_amdgcn_cvt_pk_bf16_f32(a, b);   // low = a, high = b, RNE
    return __builtin_bit_cast(unsigned int, r);
#else
    unsigned int ua = __float_as_uint(a);
    unsigned int ub = __float_as_uint(b);
    ua = (ua + 0x7FFFu + ((ua >> 16) & 1u)) >> 16;
    ub = (ub + 0x7FFFu + ((ub >> 16) & 1u)) & 0xFFFF0000u;
    return (ua & 0xFFFFu) | ub;
#endif
}

__device__ __forceinline__ float bf16_to_f(unsigned short s) {
    return __uint_as_float(((unsigned int)s) << 16);
}

// ============================================================================
// k1: hist (padded counters) + u16 rank, striped 1:2 with independent
//     streaming work.
// ============================================================================
__global__ void hist_rank_kernel(const int* __restrict__ eidx, const float* __restrict__ coord,
                                 const float* __restrict__ We2,
                                 const float* __restrict__ Wc1, const float* __restrict__ Wn1,
                                 const float* __restrict__ Wn2,
                                 int* __restrict__ histp, unsigned short* __restrict__ rank,
                                 float4* __restrict__ coord4,
                                 unsigned short* __restrict__ Wt2,
                                 unsigned short* __restrict__ Wtc1, unsigned short* __restrict__ Wtn1,
                                 unsigned short* __restrict__ Wtn2,
                                 float* __restrict__ aggz)
{
    const int g = blockIdx.x;
    if (g < 3750 && (g % 3) == 0) {
        const int i = ((g / 3) * 256 + threadIdx.x) * 4;
        const int4 r = *(const int4*)(eidx + i);
        const int kx = atomicAdd(&histp[r.x * HPAD], 1);
        const int ky = atomicAdd(&histp[r.y * HPAD], 1);
        const int kz = atomicAdd(&histp[r.z * HPAD], 1);
        const int kw = atomicAdd(&histp[r.w * HPAD], 1);
        *(ushort4*)(rank + i) = make_ushort4((unsigned short)kx, (unsigned short)ky,
                                             (unsigned short)kz, (unsigned short)kw);
        return;
    }
    const int s = (g < 3750) ? (g - g / 3 - 1) : (g - 1250);
    if (s < 157) {
        const int n = s * 256 + threadIdx.x;
        if (n < N_NODES)
            coord4[n] = make_float4(coord[n * 3 + 0], coord[n * 3 + 1], coord[n * 3 + 2], 0.f);
    } else if (s < 237) {
        const int t = (s - 157) * 256 + threadIdx.x;
        if (t < 4096)       { Wt2[t]  = f2bf(We2[(t & 63) * 64 + (t >> 6)]); }
        else if (t < 8192)  { int u = t - 4096;  Wtc1[u] = f2bf(Wc1[(u & 63) * 64 + (u >> 6)]); }
        else if (t < 16384) { int u = t - 8192;  Wtn1[u] = f2bf(Wn1[(u & 127) * 64 + (u >> 7)]); }
        else if (t < 20480) { int u = t - 16384; Wtn2[u] = f2bf(Wn2[(u & 63) * 64 + (u >> 6)]); }
    } else {
        const int i = ((s - 237) * 256 + threadIdx.x) * 4;
        if (i < N_NODES * 67)
            *(float4*)(aggz + i) = make_float4(0.f, 0.f, 0.f, 0.f);
    }
}

// ============================================================================
// k2a: compact padded hist -> cnt  PLUS  P-GEMM (P[n] = h[n]@We1 halves, f32)
// ============================================================================
__global__ __launch_bounds__(256) void compact_pgemm_kernel(
    const int* __restrict__ histp, int* __restrict__ cnt,
    const float* __restrict__ h, const float* __restrict__ We1,
    float* __restrict__ P)
{
    const int b = blockIdx.x;
    if (b < 157) {
        const int n = b * 256 + threadIdx.x;
        if (n < N_NODES) cnt[n] = histp[n * HPAD];
        return;
    }
    __shared__ __align__(16) unsigned short Hs[64 * 72];
    __shared__ __align__(16) unsigned short Wa[64 * 72];
    __shared__ __align__(16) unsigned short Wb[64 * 72];
    const int t = threadIdx.x;
    const int nbase = (b - 157) * 64;

    {
        const int nl = t >> 2, seg = t & 3;
        const float* hp = h + (size_t)(nbase + nl) * 64 + seg * 16;
        const float4 v0 = *(const float4*)(hp + 0);
        const float4 v1 = *(const float4*)(hp + 4);
        const float4 v2 = *(const float4*)(hp + 8);
        const float4 v3 = *(const float4*)(hp + 12);
        uint4 a, c;
        a.x = pack_bf2(v0.x, v0.y); a.y = pack_bf2(v0.z, v0.w);
        a.z = pack_bf2(v1.x, v1.y); a.w = pack_bf2(v1.z, v1.w);
        c.x = pack_bf2(v2.x, v2.y); c.y = pack_bf2(v2.z, v2.w);
        c.z = pack_bf2(v3.x, v3.y); c.w = pack_bf2(v3.z, v3.w);
        *(uint4*)&Hs[nl * 72 + seg * 16 + 0] = a;
        *(uint4*)&Hs[nl * 72 + seg * 16 + 8] = c;
    }
    {
        const int out = t >> 2, seg = t & 3;
        unsigned short wa[16], wb[16];
        #pragma unroll
        for (int j = 0; j < 16; ++j) {
            const int k = seg * 16 + j;
            wa[j] = f2bf(We1[k * 64 + out]);
            wb[j] = f2bf(We1[(64 + k) * 64 + out]);
        }
        *(uint4*)&Wa[out * 72 + seg * 16 + 0] = *(const uint4*)&wa[0];
        *(uint4*)&Wa[out * 72 + seg * 16 + 8] = *(const uint4*)&wa[8];
        *(uint4*)&Wb[out * 72 + seg * 16 + 0] = *(const uint4*)&wb[0];
        *(uint4*)&Wb[out * 72 + seg * 16 + 8] = *(const uint4*)&wb[8];
    }
    __syncthreads();

    const int wave = t >> 6, L = t & 63;
    const int q = L >> 4, lc = L & 15;
    const int wbase = wave * 16;

    f32x4 acc[4][2];
    #pragma unroll
    for (int ot = 0; ot < 4; ++ot)
        #pragma unroll
        for (int hf = 0; hf < 2; ++hf)
            #pragma unroll
            for (int i = 0; i < 4; ++i) acc[ot][hf][i] = 0.0f;

    #pragma unroll
    for (int ks = 0; ks < 2; ++ks) {
        const bf16x8 bfr = *(const bf16x8*)&Hs[(wbase + lc) * 72 + ks * 32 + q * 8];
        #pragma unroll
        for (int ot = 0; ot < 4; ++ot) {
            const bf16x8 afa = *(const bf16x8*)&Wa[(ot * 16 + lc) * 72 + ks * 32 + q * 8];
            acc[ot][0] = MFMA16(afa, bfr, acc[ot][0]);
            const bf16x8 afb = *(const bf16x8*)&Wb[(ot * 16 + lc) * 72 + ks * 32 + q * 8];
            acc[ot][1] = MFMA16(afb, bfr, acc[ot][1]);
        }
    }
    float* pr = P + (size_t)(nbase + wbase + lc) * 128;
    #pragma unroll
    for (int ot = 0; ot < 4; ++ot) {
        *(f32x4*)(pr + ot * 16 + q * 4)      = acc[ot][0];
        *(f32x4*)(pr + 64 + ot * 16 + q * 4) = acc[ot][1];
    }
}

// ============================================================================
// k2b: single-block scan; offs[0..N_NODES] inclusive sentinel
// ============================================================================
__global__ __launch_bounds__(1024) void scan_kernel(const int* __restrict__ cnt,
                                                    int* __restrict__ offs) {
    __shared__ int wtot[16];
    __shared__ int carry_s;
    const int t = threadIdx.x;
    const int wave = t >> 6, lane = t & 63;
    if (t == 0) carry_s = 0;
    __syncthreads();
    for (int base = 0; base < N_NODES; base += 8192) {
        const int idx = base + t * 8;
        int v[8];
        if (idx + 8 <= N_NODES) {
            const int4 a = *(const int4*)(cnt + idx);
            const int4 b = *(const int4*)(cnt + idx + 4);
            v[0] = a.x; v[1] = a.y; v[2] = a.z; v[3] = a.w;
            v[4] = b.x; v[5] = b.y; v[6] = b.z; v[7] = b.w;
        } else {
            #pragma unroll
            for (int j = 0; j < 8; ++j) v[j] = (idx + j < N_NODES) ? cnt[idx + j] : 0;
        }
        int s = 0;
        #pragma unroll
        for (int j = 0; j < 8; ++j) s += v[j];
        int S = s;
        #pragma unroll
        for (int d = 1; d < 64; d <<= 1) {
            const int u = __shfl_up(S, d, 64);
            if (lane >= d) S += u;
        }
        if (lane == 63) wtot[wave] = S;
        __syncthreads();
        if (wave == 0 && lane < 16) {
            int w = wtot[lane];
            #pragma unroll
            for (int d = 1; d < 16; d <<= 1) {
                const int u = __shfl_up(w, d, 64);
                if (lane >= d) w += u;
            }
            wtot[lane] = w;
        }
        __syncthreads();
        const int wb = (wave == 0) ? 0 : wtot[wave - 1];
        int run = carry_s + wb + (S - s);
        #pragma unroll
        for (int j = 0; j < 8; ++j) {
            if (idx + j < N_NODES) offs[idx + j] = run;
            run += v[j];
        }
        __syncthreads();
        if (t == 0) carry_s += wtot[15];
        __syncthreads();
    }
    if (t == 0) offs[N_NODES] = N_EDGES;
}

// ============================================================================
// k3: scatter 8B payloads (rc, mask) via offs[r]+rank[e] (NO atomics) + h pack.
// ============================================================================
__global__ void scatter_prep_kernel(const int* __restrict__ eidx, const float* __restrict__ emask,
                                    const unsigned short* __restrict__ rank,
                                    const int* __restrict__ offs,
                                    uint2* __restrict__ payload,
                                    const float* __restrict__ h,
                                    unsigned short* __restrict__ h_bf)
{
    const int b = blockIdx.x;
    if (b < 1250) {
        const int i = (b * 256 + threadIdx.x) * 4;
        const int4 r = *(const int4*)(eidx + i);
        const int4 c = *(const int4*)(eidx + N_EDGES + i);
        const float4 mk = *(const float4*)(emask + i);
        const ushort4 k = *(const ushort4*)(rank + i);
        #pragma unroll
        for (int j = 0; j < 4; ++j) {
            const int rj = (&r.x)[j], cj = (&c.x)[j];
            const int slot = offs[rj] + (int)(&k.x)[j];
            payload[slot] = make_uint2((unsigned)rj | ((unsigned)cj << 16),
                                       __float_as_uint((&mk.x)[j]));
        }
    } else {
        const int i = ((b - 1250) * 256 + threadIdx.x) * 4;   // exactly covers 2,560,000
        const float4 v = *(const float4*)(h + i);
        *(uint2*)(h_bf + i) = make_uint2(pack_bf2(v.x, v.y), pack_bf2(v.z, v.w));
    }
}

// ============================================================================
// k4: edge kernel — 128-edge blocks, LDS 20480B.  launch_bounds(256, 6):
//     85-VGPR budget (fits the live state, R7's forced 64 cap spilled) ->
//     24 waves/CU, 1.5x R6's TLP, clean of scratch traffic.
// ============================================================================
__global__ __launch_bounds__(256, 6) void egcl_edge_mfma(
    const float* __restrict__ P,
    const uint2* __restrict__ payload,
    const int* __restrict__ offs_g,
    const float4* __restrict__ coord4,
    const float* __restrict__ We1, const float* __restrict__ be1,
    const float* __restrict__ be2, const float* __restrict__ bc1,
    const float* __restrict__ Wc2,
    const unsigned short* __restrict__ Wt2,
    const unsigned short* __restrict__ Wtc1,
    float* __restrict__ agg, float* __restrict__ aggc)
{
    __shared__ __align__(16) unsigned short A[128 * 72];   // 18432 B
    __shared__ float dif_s[384];                           //  1536 B
    __shared__ float cval_s[128];                          //   512 B

    const int t = threadIdx.x;
    const int w = t >> 6, L = t & 63;
    const int q = L >> 4, lc = L & 15;
    const int ebase = blockIdx.x * 128;
    const int rbase = w * 32;
    const int el = rbase + (L & 31);      // this lane's edge (lanes 32-63 duplicate 0-31)

    // ---- meta: 8B payload + 2 L2-resident coord4 gathers ----
    int my_r, my_c;
    float my_rad, my_msk;
    {
        const uint2 pl = payload[ebase + el];
        my_r = (int)(pl.x & 0xFFFFu);
        my_c = (int)(pl.x >> 16);
        my_msk = __uint_as_float(pl.y);
        const float4 cr = coord4[my_r];
        const float4 cc = coord4[my_c];
        const float d0 = cr.x - cc.x, d1 = cr.y - cc.y, d2 = cr.z - cc.z;
        my_rad = d0 * d0 + d1 * d1 + d2 * d2;
        if (L < 32) { dif_s[el * 3 + 0] = d0; dif_s[el * 3 + 1] = d1; dif_s[el * 3 + 2] = d2; }
        if (t == 0)   *(int*)&A[64] = my_r;   // n0 (edge 0) in row-0 padding
        if (t == 223) *(int*)&A[66] = my_r;   // n1 (edge 127: wave 3, lane 31)
    }

    // per-et indices / rad / mask via shfl (lane et*16+lc holds edge rbase+et*16+lc)
    int r_et[2], c_et[2];
    float rad_et[2], mk_et[2];
    #pragma unroll
    for (int et = 0; et < 2; ++et) {
        r_et[et]   = __shfl(my_r, et * 16 + lc, 64);
        c_et[et]   = __shfl(my_c, et * 16 + lc, 64);
        rad_et[et] = __shfl(my_rad, et * 16 + lc, 64);
        mk_et[et]  = __shfl(my_msk, et * 16 + lc, 64);
    }

    // ---- layer1 = bias + rad*w + P[row] + P[col] (f32, no MFMA) ----
    f32x4 acc[4][2];   // [ot][et]
    #pragma unroll
    for (int ot = 0; ot < 4; ++ot) {
        const float4 bv = *(const float4*)(be1 + ot * 16 + q * 4);
        const float4 wv = *(const float4*)(We1 + 128 * 64 + ot * 16 + q * 4);
        #pragma unroll
        for (int et = 0; et < 2; ++et) {
            const float rad = rad_et[et];
            acc[ot][et][0] = fmaf(rad, wv.x, bv.x);
            acc[ot][et][1] = fmaf(rad, wv.y, bv.y);
            acc[ot][et][2] = fmaf(rad, wv.z, bv.z);
            acc[ot][et][3] = fmaf(rad, wv.w, bv.w);
        }
    }
    #pragma unroll
    for (int et = 0; et < 2; ++et) {
        const float* p1 = P + (size_t)r_et[et] * 128;
        const float* p2 = P + (size_t)c_et[et] * 128 + 64;
        #pragma unroll
        for (int ot = 0; ot < 4; ++ot) {
            const f32x4 a = *(const f32x4*)(p1 + ot * 16 + q * 4);
            const f32x4 b = *(const f32x4*)(p2 + ot * 16 + q * 4);
            acc[ot][et][0] += a[0] + b[0];
            acc[ot][et][1] += a[1] + b[1];
            acc[ot][et][2] += a[2] + b[2];
            acc[ot][et][3] += a[3] + b[3];
        }
    }

    // ---- m1 = silu -> A ----
    #pragma unroll
    for (int et = 0; et < 2; ++et) {
        const int row = rbase + et * 16 + lc;
        #pragma unroll
        for (int ot = 0; ot < 4; ++ot) {
            uint2 p;
            p.x = pack_bf2(fast_silu(acc[ot][et][0]), fast_silu(acc[ot][et][1]));
            p.y = pack_bf2(fast_silu(acc[ot][et][2]), fast_silu(acc[ot][et][3]));
            *(uint2*)&A[row * 72 + ot * 16 + q * 4] = p;
        }
    }

    // ---- layer2 ----
    f32x4 acc2[4][2];
    #pragma unroll
    for (int ot = 0; ot < 4; ++ot) {
        const float4 bv = *(const float4*)(be2 + ot * 16 + q * 4);
        #pragma unroll
        for (int et = 0; et < 2; ++et) {
            acc2[ot][et][0] = bv.x; acc2[ot][et][1] = bv.y;
            acc2[ot][et][2] = bv.z; acc2[ot][et][3] = bv.w;
        }
    }
    #pragma unroll
    for (int ks = 0; ks < 2; ++ks) {
        bf16x8 bfr[2];
        #pragma unroll
        for (int et = 0; et < 2; ++et)
            bfr[et] = *(const bf16x8*)&A[(rbase + et * 16 + lc) * 72 + ks * 32 + q * 8];
        #pragma unroll
        for (int ot = 0; ot < 4; ++ot) {
            const bf16x8 af = *(const bf16x8*)&Wt2[(ot * 16 + lc) * 64 + ks * 32 + q * 8];
            #pragma unroll
            for (int et = 0; et < 2; ++et)
                acc2[ot][et] = MFMA16(af, bfr[et], acc2[ot][et]);
        }
    }

    // ---- m = silu * mask -> A ----
    #pragma unroll
    for (int et = 0; et < 2; ++et) {
        const int row = rbase + et * 16 + lc;
        const float mk = mk_et[et];
        #pragma unroll
        for (int ot = 0; ot < 4; ++ot) {
            uint2 p;
            p.x = pack_bf2(fast_silu(acc2[ot][et][0]) * mk, fast_silu(acc2[ot][et][1]) * mk);
            p.y = pack_bf2(fast_silu(acc2[ot][et][2]) * mk, fast_silu(acc2[ot][et][3]) * mk);
            *(uint2*)&A[row * 72 + ot * 16 + q * 4] = p;
        }
    }

    // ---- coord mlp ----
    f32x4 acc3[4][2];
    #pragma unroll
    for (int ot = 0; ot < 4; ++ot) {
        const float4 bv = *(const float4*)(bc1 + ot * 16 + q * 4);
        #pragma unroll
        for (int et = 0; et < 2; ++et) {
            acc3[ot][et][0] = bv.x; acc3[ot][et][1] = bv.y;
            acc3[ot][et][2] = bv.z; acc3[ot][et][3] = bv.w;
        }
    }
    #pragma unroll
    for (int ks = 0; ks < 2; ++ks) {
        bf16x8 bfr[2];
        #pragma unroll
        for (int et = 0; et < 2; ++et)
            bfr[et] = *(const bf16x8*)&A[(rbase + et * 16 + lc) * 72 + ks * 32 + q * 8];
        #pragma unroll
        for (int ot = 0; ot < 4; ++ot) {
            const bf16x8 af = *(const bf16x8*)&Wtc1[(ot * 16 + lc) * 64 + ks * 32 + q * 8];
            #pragma unroll
            for (int et = 0; et < 2; ++et)
                acc3[ot][et] = MFMA16(af, bfr[et], acc3[ot][et]);
        }
    }
    {
        float4 wv[4];
        #pragma unroll
        for (int ot = 0; ot < 4; ++ot) wv[ot] = *(const float4*)(Wc2 + ot * 16 + q * 4);
        #pragma unroll
        for (int et = 0; et < 2; ++et) {
            float s = 0.0f;
            #pragma unroll
            for (int ot = 0; ot < 4; ++ot) {
                s = fmaf(fast_silu(acc3[ot][et][0]), wv[ot].x, s);
                s = fmaf(fast_silu(acc3[ot][et][1]), wv[ot].y, s);
                s = fmaf(fast_silu(acc3[ot][et][2]), wv[ot].z, s);
                s = fmaf(fast_silu(acc3[ot][et][3]), wv[ot].w, s);
            }
            s += __shfl_xor(s, 16, 64);
            s += __shfl_xor(s, 32, 64);
            if (q == 0)
                cval_s[rbase + et * 16 + lc] = s * mk_et[et];
        }
    }

    __syncthreads();   // whole block's m / cval / dif now valid

    // ---- fused segmented aggregation (128-slot window) ----
    {
        const int n0 = *(const int*)&A[64];
        const int n1 = *(const int*)&A[66];
        const int half = L >> 5;          // 0: even slots, 1: odd slots
        const int cp = L & 31;            // column pair (cols 2cp, 2cp+1)
        const bool c3 = (cp < 3);
        for (int n = n0 + w; n <= n1; n += 4) {
            const int os = offs_g[n];
            const int oe = offs_g[n + 1];
            const int s0 = max(os - ebase, 0);
            const int s1 = min(oe - ebase, 128);
            float sx = 0.0f, sy = 0.0f, t3 = 0.0f;
            int slot = s0 + half;
            for (; slot + 2 < s1; slot += 4) {
                const unsigned ua = *(const unsigned*)&A[(slot + 0) * 72 + cp * 2];
                const unsigned ub = *(const unsigned*)&A[(slot + 2) * 72 + cp * 2];
                sx += __uint_as_float(ua << 16) + __uint_as_float(ub << 16);
                sy += __uint_as_float(ua & 0xFFFF0000u) + __uint_as_float(ub & 0xFFFF0000u);
                if (c3) {
                    t3 = fmaf(dif_s[(slot + 0) * 3 + cp], cval_s[slot + 0], t3);
                    t3 = fmaf(dif_s[(slot + 2) * 3 + cp], cval_s[slot + 2], t3);
                }
            }
            if (slot < s1) {
                const unsigned ua = *(const unsigned*)&A[slot * 72 + cp * 2];
                sx += __uint_as_float(ua << 16);
                sy += __uint_as_float(ua & 0xFFFF0000u);
                if (c3) t3 = fmaf(dif_s[slot * 3 + cp], cval_s[slot], t3);
            }
            sx += __shfl_xor(sx, 32, 64);
            sy += __shfl_xor(sy, 32, 64);
            if (c3) t3 += __shfl_xor(t3, 32, 64);
            const bool interior = (os >= ebase) && (oe <= ebase + 128);
            if (half == 0) {
                if (interior) {
                    float2 v; v.x = sx; v.y = sy;
                    *(float2*)&agg[(size_t)n * 64 + cp * 2] = v;
                    if (c3) aggc[n * 3 + cp] = t3;
                } else {
                    atomicAdd(&agg[(size_t)n * 64 + cp * 2 + 0], sx);
                    atomicAdd(&agg[(size_t)n * 64 + cp * 2 + 1], sy);
                    if (c3) atomicAdd(&aggc[n * 3 + cp], t3);
                }
            }
        }
    }
}

// ============================================================================
// k5: node MLP + coord output — 64-node tiles; degree from offs diff
// ============================================================================
__global__ __launch_bounds__(256, 8) void egcl_node_coord(
    const unsigned short* __restrict__ h_bf, const float* __restrict__ agg,
    const float* __restrict__ bn1, const float* __restrict__ bn2,
    const unsigned short* __restrict__ Wtn1, const unsigned short* __restrict__ Wtn2,
    const float* __restrict__ coord, const float* __restrict__ aggc,
    const int* __restrict__ offs,
    float* __restrict__ hout, float* __restrict__ cout)
{
    if (blockIdx.x >= NB5) {
        const int i = (blockIdx.x - NB5) * 256 + threadIdx.x;
        if (i < N_NODES * 3) {
            const int node = i / 3;
            const float c = fmaxf((float)(offs[node + 1] - offs[node]), 1.0f);
            cout[i] = coord[i] + aggc[i] * __builtin_amdgcn_rcpf(c);
        }
        return;
    }

    __shared__ __align__(16) unsigned short A[64 * 136];
    const int t = threadIdx.x;
    const int wave = t >> 6, L = t & 63;
    const int q = L >> 4, lc = L & 15;
    const int nbase = blockIdx.x * 64;
    const int rbase = wave * 16;

    #pragma unroll
    for (int it = 0; it < 8; ++it) {
        const int idx = it * 256 + t;         // 0..2047 = 64 rows x 32 parts
        const int ln = idx >> 5, part = idx & 31;
        const int node = nbase + ln;
        uint2 u;
        if (part < 16) {
            u = *(const uint2*)(h_bf + (size_t)node * 64 + part * 4);
        } else {
            const float4 v = *(const float4*)(agg + (size_t)node * 64 + (part - 16) * 4);
            u = make_uint2(pack_bf2(v.x, v.y), pack_bf2(v.z, v.w));
        }
        *(uint2*)&A[ln * 136 + part * 4] = u;
    }
    __syncthreads();

    f32x4 acc1[4];
    #pragma unroll
    for (int ct = 0; ct < 4; ++ct) {
        const float b = bn1[ct * 16 + lc];
        #pragma unroll
        for (int i = 0; i < 4; ++i) acc1[ct][i] = b;
    }
    #pragma unroll
    for (int ks = 0; ks < 4; ++ks) {
        const bf16x8 af = *(const bf16x8*)&A[(rbase + lc) * 136 + ks * 32 + q * 8];
        #pragma unroll
        for (int ct = 0; ct < 4; ++ct) {
            const bf16x8 bf = *(const bf16x8*)&Wtn1[(ct * 16 + lc) * 128 + ks * 32 + q * 8];
            acc1[ct] = MFMA16(af, bf, acc1[ct]);
        }
    }
    __syncthreads();

    #pragma unroll
    for (int ct = 0; ct < 4; ++ct)
        #pragma unroll
        for (int i = 0; i < 4; ++i) {
            const int row = rbase + q * 4 + i;
            A[row * 72 + ct * 16 + lc] = f2bf(fast_silu(acc1[ct][i]));
        }
    __syncthreads();

    f32x4 acc2[4];
    #pragma unroll
    for (int ct = 0; ct < 4; ++ct) {
        const float b = bn2[ct * 16 + lc];
        #pragma unroll
        for (int i = 0; i < 4; ++i) acc2[ct][i] = b;
    }
    #pragma unroll
    for (int ks = 0; ks < 2; ++ks) {
        const bf16x8 af = *(const bf16x8*)&A[(rbase + lc) * 72 + ks * 32 + q * 8];
        #pragma unroll
        for (int ct = 0; ct < 4; ++ct) {
            const bf16x8 bf = *(const bf16x8*)&Wtn2[(ct * 16 + lc) * 64 + ks * 32 + q * 8];
            acc2[ct] = MFMA16(af, bf, acc2[ct]);
        }
    }

    #pragma unroll
    for (int ct = 0; ct < 4; ++ct)
        #pragma unroll
        for (int i = 0; i < 4; ++i) {
            const int node = nbase + rbase + q * 4 + i;
            hout[(size_t)node * 64 + ct * 16 + lc] = acc2[ct][i];
        }
}

// ============================================================================
// launch
// ============================================================================
extern "C" void kernel_launch(void* const* d_in, const int* in_sizes, int n_in,
                              void* d_out, int out_size, void* d_ws, size_t ws_size,
                              hipStream_t stream)
{
    const float* h     = (const float*)d_in[0];
    const float* coord = (const float*)d_in[1];
    const int*   eidx  = (const int*)d_in[2];
    const float* emask = (const float*)d_in[3];
    const float* We1   = (const float*)d_in[4];
    const float* be1   = (const float*)d_in[5];
    const float* We2   = (const float*)d_in[6];
    const float* be2   = (const float*)d_in[7];
    const float* Wn1   = (const float*)d_in[8];
    const float* bn1   = (const float*)d_in[9];
    const float* Wn2   = (const float*)d_in[10];
    const float* bn2   = (const float*)d_in[11];
    const float* Wc1   = (const float*)d_in[12];
    const float* bc1   = (const float*)d_in[13];
    const float* Wc2   = (const float*)d_in[14];

    float* hout = (float*)d_out;
    float* cout = hout + (size_t)N_NODES * 64;

    // ws layout (all chunks 16B-multiples)
    char* p = (char*)d_ws;
    float* agg  = (float*)p;                      p += (size_t)N_NODES * 64 * 4;   // 10.24 MB
    float* aggc = (float*)p;                      p += (size_t)N_NODES * 3 * 4;    // 0.48 MB (contiguous with agg for zeroing)
    int* histp  = (int*)p;                        p += (size_t)N_NODES * HPAD * 4; // 2.56 MB padded hist
    int* offs   = (int*)p;                        p += (size_t)(N_NODES + 4) * 4;  // 40001 used
    int* cnt    = (int*)p;                        p += (size_t)N_NODES * 4;        // 0.16 MB
    unsigned short* rank = (unsigned short*)p;    p += (size_t)N_EDGES * 2;        // 2.56 MB (u16)
    uint2* payload = (uint2*)p;                   p += (size_t)N_EDGES * 8;        // 10.24 MB
    unsigned short* h_bf = (unsigned short*)p;    p += (size_t)N_NODES * 64 * 2;   // 5.12 MB
    float4* coord4 = (float4*)p;                  p += (size_t)N_NODES * 16;       // 0.64 MB
    float* P = (float*)p;                         p += (size_t)N_NODES * 128 * 4;  // 20.48 MB node projections
    unsigned short* Wt2  = (unsigned short*)p;    p += 4096 * 2;
    unsigned short* Wtc1 = (unsigned short*)p;    p += 4096 * 2;
    unsigned short* Wtn1 = (unsigned short*)p;    p += 8192 * 2;
    unsigned short* Wtn2 = (unsigned short*)p;    p += 4096 * 2;

    hipMemsetAsync(histp, 0, (size_t)N_NODES * HPAD * 4, stream);   // 2.56 MB
    hist_rank_kernel<<<K1_GRID, 256, 0, stream>>>(eidx, coord, We2, Wc1, Wn1, Wn2,
                                                  histp, rank, coord4,
                                                  Wt2, Wtc1, Wtn1, Wtn2, agg);
    compact_pgemm_kernel<<<782, 256, 0, stream>>>(histp, cnt, h, We1, P);
    scan_kernel<<<1, 1024, 0, stream>>>(cnt, offs);
    scatter_prep_kernel<<<3750, 256, 0, stream>>>(eidx, emask, rank, offs, payload, h, h_bf);
    egcl_edge_mfma<<<N_EDGES / 128, 256, 0, stream>>>(
        P, payload, offs, coord4,
        We1, be1, be2, bc1, Wc2, Wt2, Wtc1, agg, aggc);
    egcl_node_coord<<<NB5 + COORD_BLOCKS, 256, 0, stream>>>(
        h_bf, agg, bn1, bn2, Wtn1, Wtn2, coord, aggc, offs, hout, cout);
}

// Round 9
// 342.591 us; speedup vs baseline: 1.2695x; 1.0518x over previous
//
#include <hip/hip_runtime.h>
#include <stdint.h>

#define N_NODES 40000
#define N_EDGES 1280000

// k1 block-role layout: 1250 atomic blocks striped 1:2 with 2855 streaming blocks
#define K1_GRID 4105          // 1250 hist + 157 coord4 + 80 wpack + 2618 zero
#define NB5 625               // k5: 64-node tiles
#define COORD_BLOCKS 469      // ceil(40000*3/256)

typedef __attribute__((ext_vector_type(8))) short bf16x8;   // 8 bf16 in 4 VGPRs
typedef __attribute__((ext_vector_type(4))) float f32x4;    // MFMA C/D

#define MFMA16(a, b, c) __builtin_amdgcn_mfma_f32_16x16x32_bf16((a), (b), (c), 0, 0, 0)

#if defined(__has_builtin)
#if __has_builtin(__builtin_amdgcn_cvt_pk_bf16_f32)
#define HAS_CVT_PK_BF16 1
#endif
#endif

// ---------- helpers ----------
__device__ __forceinline__ float fast_silu(float x) {
    float e = __expf(-x);
    return x * __builtin_amdgcn_rcpf(1.0f + e);
}

__device__ __forceinline__ unsigned short f2bf(float x) {
    unsigned int u = __float_as_uint(x);
    u = (u + 0x7FFFu + ((u >> 16) & 1u)) >> 16;
    return (unsigned short)u;
}

__device__ __forceinline__ unsigned int pack_bf2(float a, float b) {
#ifdef HAS_CVT_PK_BF16
    typedef __attribute__((ext_vector_type(2))) __bf16 bf2_t;
    bf2_t r = __builtin_amdgcn_cvt_pk_bf16_f32(a, b);   // low = a, high = b, RNE
    return __builtin_bit_cast(unsigned int, r);
#else
    unsigned int ua = __float_as_uint(a);
    unsigned int ub = __float_as_uint(b);
    ua = (ua + 0x7FFFu + ((ua >> 16) & 1u)) >> 16;
    ub = (ub + 0x7FFFu + ((ub >> 16) & 1u)) & 0xFFFF0000u;
    return (ua & 0xFFFFu) | ub;
#endif
}

__device__ __forceinline__ float bf16_to_f(unsigned short s) {
    return __uint_as_float(((unsigned int)s) << 16);
}

// XCC id via s_getreg(HW_REG_XCC_ID): id=20, offset=0, size=32
// encoding: ((size-1)<<11) | (offset<<6) | id  ->  (31<<11) | 20
// Masked to [0,7]. Correctness does NOT depend on the value being right:
// k3 re-reads the xcd that k1 wrote, so any consistent value works.
__device__ __forceinline__ int xcc_id() {
    return (int)(__builtin_amdgcn_s_getreg((31 << 11) | 20) & 7u);
}

// ============================================================================
// k1: PER-XCD private histograms (hist_x[xcd][node], each copy touched only
//     by blocks on that XCD -> lines stay in the local L2, no cross-XCD
//     ping-pong) + u16 rank packed as (xcd<<12)|local_rank.
//     Striped 1:2 with independent streaming work.
// ============================================================================
__global__ void hist_rank_kernel(const int* __restrict__ eidx, const float* __restrict__ coord,
                                 const float* __restrict__ We2,
                                 const float* __restrict__ Wc1, const float* __restrict__ Wn1,
                                 const float* __restrict__ Wn2,
                                 int* __restrict__ hist_x, unsigned short* __restrict__ rank,
                                 float4* __restrict__ coord4,
                                 unsigned short* __restrict__ Wt2,
                                 unsigned short* __restrict__ Wtc1, unsigned short* __restrict__ Wtn1,
                                 unsigned short* __restrict__ Wtn2,
                                 float* __restrict__ aggz)
{
    const int g = blockIdx.x;
    if (g < 3750 && (g % 3) == 0) {
        const int xcd = xcc_id();
        int* hx = hist_x + (size_t)xcd * N_NODES;
        const unsigned xb = (unsigned)xcd << 12;
        const int i = ((g / 3) * 256 + threadIdx.x) * 4;
        const int4 r = *(const int4*)(eidx + i);
        const int kx = atomicAdd(&hx[r.x], 1);
        const int ky = atomicAdd(&hx[r.y], 1);
        const int kz = atomicAdd(&hx[r.z], 1);
        const int kw = atomicAdd(&hx[r.w], 1);
        *(ushort4*)(rank + i) = make_ushort4((unsigned short)(kx | xb), (unsigned short)(ky | xb),
                                             (unsigned short)(kz | xb), (unsigned short)(kw | xb));
        return;
    }
    const int s = (g < 3750) ? (g - g / 3 - 1) : (g - 1250);
    if (s < 157) {
        const int n = s * 256 + threadIdx.x;
        if (n < N_NODES)
            coord4[n] = make_float4(coord[n * 3 + 0], coord[n * 3 + 1], coord[n * 3 + 2], 0.f);
    } else if (s < 237) {
        const int t = (s - 157) * 256 + threadIdx.x;
        if (t < 4096)       { Wt2[t]  = f2bf(We2[(t & 63) * 64 + (t >> 6)]); }
        else if (t < 8192)  { int u = t - 4096;  Wtc1[u] = f2bf(Wc1[(u & 63) * 64 + (u >> 6)]); }
        else if (t < 16384) { int u = t - 8192;  Wtn1[u] = f2bf(Wn1[(u & 127) * 64 + (u >> 7)]); }
        else if (t < 20480) { int u = t - 16384; Wtn2[u] = f2bf(Wn2[(u & 63) * 64 + (u >> 6)]); }
    } else {
        const int i = ((s - 237) * 256 + threadIdx.x) * 4;
        if (i < N_NODES * 67)
            *(float4*)(aggz + i) = make_float4(0.f, 0.f, 0.f, 0.f);
    }
}

// ============================================================================
// k2a: per-node prefix over the 8 XCD copies -> xb[n][8] (exclusive) + cnt[n]
//      PLUS P-GEMM (P[n] = h[n]@We1 halves, f32).
//   blocks [0,157)   : xcd-prefix
//   blocks [157,782) : P-GEMM, 64-node tiles
// ============================================================================
__global__ __launch_bounds__(256) void prefix_pgemm_kernel(
    const int* __restrict__ hist_x, int* __restrict__ xb, int* __restrict__ cnt,
    const float* __restrict__ h, const float* __restrict__ We1,
    float* __restrict__ P)
{
    const int b = blockIdx.x;
    if (b < 157) {
        const int n = b * 256 + threadIdx.x;
        if (n < N_NODES) {
            int run = 0;
            int out[8];
            #pragma unroll
            for (int x = 0; x < 8; ++x) {
                out[x] = run;
                run += hist_x[(size_t)x * N_NODES + n];
            }
            *(int4*)(xb + n * 8 + 0) = make_int4(out[0], out[1], out[2], out[3]);
            *(int4*)(xb + n * 8 + 4) = make_int4(out[4], out[5], out[6], out[7]);
            cnt[n] = run;
        }
        return;
    }
    __shared__ __align__(16) unsigned short Hs[64 * 72];
    __shared__ __align__(16) unsigned short Wa[64 * 72];
    __shared__ __align__(16) unsigned short Wb[64 * 72];
    const int t = threadIdx.x;
    const int nbase = (b - 157) * 64;

    {
        const int nl = t >> 2, seg = t & 3;
        const float* hp = h + (size_t)(nbase + nl) * 64 + seg * 16;
        const float4 v0 = *(const float4*)(hp + 0);
        const float4 v1 = *(const float4*)(hp + 4);
        const float4 v2 = *(const float4*)(hp + 8);
        const float4 v3 = *(const float4*)(hp + 12);
        uint4 a, c;
        a.x = pack_bf2(v0.x, v0.y); a.y = pack_bf2(v0.z, v0.w);
        a.z = pack_bf2(v1.x, v1.y); a.w = pack_bf2(v1.z, v1.w);
        c.x = pack_bf2(v2.x, v2.y); c.y = pack_bf2(v2.z, v2.w);
        c.z = pack_bf2(v3.x, v3.y); c.w = pack_bf2(v3.z, v3.w);
        *(uint4*)&Hs[nl * 72 + seg * 16 + 0] = a;
        *(uint4*)&Hs[nl * 72 + seg * 16 + 8] = c;
    }
    {
        const int out = t >> 2, seg = t & 3;
        unsigned short wa[16], wb2[16];
        #pragma unroll
        for (int j = 0; j < 16; ++j) {
            const int k = seg * 16 + j;
            wa[j]  = f2bf(We1[k * 64 + out]);
            wb2[j] = f2bf(We1[(64 + k) * 64 + out]);
        }
        *(uint4*)&Wa[out * 72 + seg * 16 + 0] = *(const uint4*)&wa[0];
        *(uint4*)&Wa[out * 72 + seg * 16 + 8] = *(const uint4*)&wa[8];
        *(uint4*)&Wb[out * 72 + seg * 16 + 0] = *(const uint4*)&wb2[0];
        *(uint4*)&Wb[out * 72 + seg * 16 + 8] = *(const uint4*)&wb2[8];
    }
    __syncthreads();

    const int wave = t >> 6, L = t & 63;
    const int q = L >> 4, lc = L & 15;
    const int wbase = wave * 16;

    f32x4 acc[4][2];
    #pragma unroll
    for (int ot = 0; ot < 4; ++ot)
        #pragma unroll
        for (int hf = 0; hf < 2; ++hf)
            #pragma unroll
            for (int i = 0; i < 4; ++i) acc[ot][hf][i] = 0.0f;

    #pragma unroll
    for (int ks = 0; ks < 2; ++ks) {
        const bf16x8 bfr = *(const bf16x8*)&Hs[(wbase + lc) * 72 + ks * 32 + q * 8];
        #pragma unroll
        for (int ot = 0; ot < 4; ++ot) {
            const bf16x8 afa = *(const bf16x8*)&Wa[(ot * 16 + lc) * 72 + ks * 32 + q * 8];
            acc[ot][0] = MFMA16(afa, bfr, acc[ot][0]);
            const bf16x8 afb = *(const bf16x8*)&Wb[(ot * 16 + lc) * 72 + ks * 32 + q * 8];
            acc[ot][1] = MFMA16(afb, bfr, acc[ot][1]);
        }
    }
    float* pr = P + (size_t)(nbase + wbase + lc) * 128;
    #pragma unroll
    for (int ot = 0; ot < 4; ++ot) {
        *(f32x4*)(pr + ot * 16 + q * 4)      = acc[ot][0];
        *(f32x4*)(pr + 64 + ot * 16 + q * 4) = acc[ot][1];
    }
}

// ============================================================================
// k2b: single-block scan; offs[0..N_NODES] inclusive sentinel
// ============================================================================
__global__ __launch_bounds__(1024) void scan_kernel(const int* __restrict__ cnt,
                                                    int* __restrict__ offs) {
    __shared__ int wtot[16];
    __shared__ int carry_s;
    const int t = threadIdx.x;
    const int wave = t >> 6, lane = t & 63;
    if (t == 0) carry_s = 0;
    __syncthreads();
    for (int base = 0; base < N_NODES; base += 8192) {
        const int idx = base + t * 8;
        int v[8];
        if (idx + 8 <= N_NODES) {
            const int4 a = *(const int4*)(cnt + idx);
            const int4 b = *(const int4*)(cnt + idx + 4);
            v[0] = a.x; v[1] = a.y; v[2] = a.z; v[3] = a.w;
            v[4] = b.x; v[5] = b.y; v[6] = b.z; v[7] = b.w;
        } else {
            #pragma unroll
            for (int j = 0; j < 8; ++j) v[j] = (idx + j < N_NODES) ? cnt[idx + j] : 0;
        }
        int s = 0;
        #pragma unroll
        for (int j = 0; j < 8; ++j) s += v[j];
        int S = s;
        #pragma unroll
        for (int d = 1; d < 64; d <<= 1) {
            const int u = __shfl_up(S, d, 64);
            if (lane >= d) S += u;
        }
        if (lane == 63) wtot[wave] = S;
        __syncthreads();
        if (wave == 0 && lane < 16) {
            int w = wtot[lane];
            #pragma unroll
            for (int d = 1; d < 16; d <<= 1) {
                const int u = __shfl_up(w, d, 64);
                if (lane >= d) w += u;
            }
            wtot[lane] = w;
        }
        __syncthreads();
        const int wb = (wave == 0) ? 0 : wtot[wave - 1];
        int run = carry_s + wb + (S - s);
        #pragma unroll
        for (int j = 0; j < 8; ++j) {
            if (idx + j < N_NODES) offs[idx + j] = run;
            run += v[j];
        }
        __syncthreads();
        if (t == 0) carry_s += wtot[15];
        __syncthreads();
    }
    if (t == 0) offs[N_NODES] = N_EDGES;
}

// ============================================================================
// k3: scatter 8B payloads: slot = offs[r] + xb[r][xcd] + rank (NO atomics)
//     + h pack.
// ============================================================================
__global__ void scatter_prep_kernel(const int* __restrict__ eidx, const float* __restrict__ emask,
                                    const unsigned short* __restrict__ rank,
                                    const int* __restrict__ offs, const int* __restrict__ xb,
                                    uint2* __restrict__ payload,
                                    const float* __restrict__ h,
                                    unsigned short* __restrict__ h_bf)
{
    const int b = blockIdx.x;
    if (b < 1250) {
        const int i = (b * 256 + threadIdx.x) * 4;
        const int4 r = *(const int4*)(eidx + i);
        const int4 c = *(const int4*)(eidx + N_EDGES + i);
        const float4 mk = *(const float4*)(emask + i);
        const ushort4 k = *(const ushort4*)(rank + i);
        #pragma unroll
        for (int j = 0; j < 4; ++j) {
            const int rj = (&r.x)[j], cj = (&c.x)[j];
            const int kk = (int)(&k.x)[j];
            const int slot = offs[rj] + xb[rj * 8 + (kk >> 12)] + (kk & 0xFFF);
            payload[slot] = make_uint2((unsigned)rj | ((unsigned)cj << 16),
                                       __float_as_uint((&mk.x)[j]));
        }
    } else {
        const int i = ((b - 1250) * 256 + threadIdx.x) * 4;   // exactly covers 2,560,000
        const float4 v = *(const float4*)(h + i);
        *(uint2*)(h_bf + i) = make_uint2(pack_bf2(v.x, v.y), pack_bf2(v.z, v.w));
    }
}

// ============================================================================
// k4: edge kernel — R6 winner verbatim (256-edge blocks, (256,4), 141 us).
// ============================================================================
__global__ __launch_bounds__(256, 4) void egcl_edge_mfma(
    const float* __restrict__ P,
    const uint2* __restrict__ payload,
    const int* __restrict__ offs_g,
    const float4* __restrict__ coord4,
    const float* __restrict__ We1, const float* __restrict__ be1,
    const float* __restrict__ be2, const float* __restrict__ bc1,
    const float* __restrict__ Wc2,
    const unsigned short* __restrict__ Wt2,
    const unsigned short* __restrict__ Wtc1,
    float* __restrict__ agg, float* __restrict__ aggc)
{
    __shared__ __align__(16) unsigned short A[256 * 72];
    __shared__ float dif_s[768];
    __shared__ float cval_s[256];

    const int t = threadIdx.x;
    const int w = t >> 6, L = t & 63;
    const int q = L >> 4, lc = L & 15;
    const int ebase = blockIdx.x * 256;
    const int rbase = w * 64;

    // ---- meta: 8B coalesced payload + 2 L2-resident coord4 gathers ----
    int my_r, my_c;
    float my_rad, my_msk;
    {
        const uint2 pl = payload[ebase + t];
        my_r = (int)(pl.x & 0xFFFFu);
        my_c = (int)(pl.x >> 16);
        my_msk = __uint_as_float(pl.y);
        const float4 cr = coord4[my_r];
        const float4 cc = coord4[my_c];
        const float d0 = cr.x - cc.x, d1 = cr.y - cc.y, d2 = cr.z - cc.z;
        my_rad = d0 * d0 + d1 * d1 + d2 * d2;
        dif_s[t * 3 + 0] = d0; dif_s[t * 3 + 1] = d1; dif_s[t * 3 + 2] = d2;
        if (t == 0)   *(int*)&A[64] = my_r;   // n0 in row-0 padding
        if (t == 255) *(int*)&A[66] = my_r;   // n1
    }

    // per-et indices / rad / mask via shfl (slot et*16+lc is in this wave)
    int r_et[4], c_et[4];
    float rad_et[4], mk_et[4];
    #pragma unroll
    for (int et = 0; et < 4; ++et) {
        r_et[et]   = __shfl(my_r, et * 16 + lc, 64);
        c_et[et]   = __shfl(my_c, et * 16 + lc, 64);
        rad_et[et] = __shfl(my_rad, et * 16 + lc, 64);
        mk_et[et]  = __shfl(my_msk, et * 16 + lc, 64);
    }

    // ---- layer1 = bias + rad*w + P[row] + P[col] (f32, no MFMA) ----
    f32x4 acc[4][4];   // [ot][et]
    #pragma unroll
    for (int ot = 0; ot < 4; ++ot) {
        const float4 bv = *(const float4*)(be1 + ot * 16 + q * 4);
        const float4 wv = *(const float4*)(We1 + 128 * 64 + ot * 16 + q * 4);
        #pragma unroll
        for (int et = 0; et < 4; ++et) {
            const float rad = rad_et[et];
            acc[ot][et][0] = fmaf(rad, wv.x, bv.x);
            acc[ot][et][1] = fmaf(rad, wv.y, bv.y);
            acc[ot][et][2] = fmaf(rad, wv.z, bv.z);
            acc[ot][et][3] = fmaf(rad, wv.w, bv.w);
        }
    }
    #pragma unroll
    for (int et = 0; et < 4; ++et) {
        const float* p1 = P + (size_t)r_et[et] * 128;
        const float* p2 = P + (size_t)c_et[et] * 128 + 64;
        #pragma unroll
        for (int ot = 0; ot < 4; ++ot) {
            const f32x4 a = *(const f32x4*)(p1 + ot * 16 + q * 4);
            const f32x4 b = *(const f32x4*)(p2 + ot * 16 + q * 4);
            acc[ot][et][0] += a[0] + b[0];
            acc[ot][et][1] += a[1] + b[1];
            acc[ot][et][2] += a[2] + b[2];
            acc[ot][et][3] += a[3] + b[3];
        }
    }

    // ---- m1 = silu -> A ----
    #pragma unroll
    for (int et = 0; et < 4; ++et) {
        const int row = rbase + et * 16 + lc;
        #pragma unroll
        for (int ot = 0; ot < 4; ++ot) {
            uint2 p;
            p.x = pack_bf2(fast_silu(acc[ot][et][0]), fast_silu(acc[ot][et][1]));
            p.y = pack_bf2(fast_silu(acc[ot][et][2]), fast_silu(acc[ot][et][3]));
            *(uint2*)&A[row * 72 + ot * 16 + q * 4] = p;
        }
    }

    // ---- layer2 ----
    f32x4 acc2[4][4];
    #pragma unroll
    for (int ot = 0; ot < 4; ++ot) {
        const float4 bv = *(const float4*)(be2 + ot * 16 + q * 4);
        #pragma unroll
        for (int et = 0; et < 4; ++et) {
            acc2[ot][et][0] = bv.x; acc2[ot][et][1] = bv.y;
            acc2[ot][et][2] = bv.z; acc2[ot][et][3] = bv.w;
        }
    }
    #pragma unroll
    for (int ks = 0; ks < 2; ++ks) {
        bf16x8 bfr[4];
        #pragma unroll
        for (int et = 0; et < 4; ++et)
            bfr[et] = *(const bf16x8*)&A[(rbase + et * 16 + lc) * 72 + ks * 32 + q * 8];
        #pragma unroll
        for (int ot = 0; ot < 4; ++ot) {
            const bf16x8 af = *(const bf16x8*)&Wt2[(ot * 16 + lc) * 64 + ks * 32 + q * 8];
            #pragma unroll
            for (int et = 0; et < 4; ++et)
                acc2[ot][et] = MFMA16(af, bfr[et], acc2[ot][et]);
        }
    }

    // ---- m = silu * mask -> A ----
    #pragma unroll
    for (int et = 0; et < 4; ++et) {
        const int row = rbase + et * 16 + lc;
        const float mk = mk_et[et];
        #pragma unroll
        for (int ot = 0; ot < 4; ++ot) {
            uint2 p;
            p.x = pack_bf2(fast_silu(acc2[ot][et][0]) * mk, fast_silu(acc2[ot][et][1]) * mk);
            p.y = pack_bf2(fast_silu(acc2[ot][et][2]) * mk, fast_silu(acc2[ot][et][3]) * mk);
            *(uint2*)&A[row * 72 + ot * 16 + q * 4] = p;
        }
    }

    // ---- coord mlp ----
    f32x4 acc3[4][4];
    #pragma unroll
    for (int ot = 0; ot < 4; ++ot) {
        const float4 bv = *(const float4*)(bc1 + ot * 16 + q * 4);
        #pragma unroll
        for (int et = 0; et < 4; ++et) {
            acc3[ot][et][0] = bv.x; acc3[ot][et][1] = bv.y;
            acc3[ot][et][2] = bv.z; acc3[ot][et][3] = bv.w;
        }
    }
    #pragma unroll
    for (int ks = 0; ks < 2; ++ks) {
        bf16x8 bfr[4];
        #pragma unroll
        for (int et = 0; et < 4; ++et)
            bfr[et] = *(const bf16x8*)&A[(rbase + et * 16 + lc) * 72 + ks * 32 + q * 8];
        #pragma unroll
        for (int ot = 0; ot < 4; ++ot) {
            const bf16x8 af = *(const bf16x8*)&Wtc1[(ot * 16 + lc) * 64 + ks * 32 + q * 8];
            #pragma unroll
            for (int et = 0; et < 4; ++et)
                acc3[ot][et] = MFMA16(af, bfr[et], acc3[ot][et]);
        }
    }
    {
        float4 wv[4];
        #pragma unroll
        for (int ot = 0; ot < 4; ++ot) wv[ot] = *(const float4*)(Wc2 + ot * 16 + q * 4);
        #pragma unroll
        for (int et = 0; et < 4; ++et) {
            float s = 0.0f;
            #pragma unroll
            for (int ot = 0; ot < 4; ++ot) {
                s = fmaf(fast_silu(acc3[ot][et][0]), wv[ot].x, s);
                s = fmaf(fast_silu(acc3[ot][et][1]), wv[ot].y, s);
                s = fmaf(fast_silu(acc3[ot][et][2]), wv[ot].z, s);
                s = fmaf(fast_silu(acc3[ot][et][3]), wv[ot].w, s);
            }
            s += __shfl_xor(s, 16, 64);
            s += __shfl_xor(s, 32, 64);
            if (q == 0)
                cval_s[rbase + et * 16 + lc] = s * mk_et[et];
        }
    }

    __syncthreads();   // whole block's m / cval / dif now valid

    // ---- fused segmented aggregation: lane-halves over even/odd slots,
    //      b32 (2-column) LDS reads, shfl_xor(32) combine, float2 stores ----
    {
        const int n0 = *(const int*)&A[64];
        const int n1 = *(const int*)&A[66];
        const int half = L >> 5;          // 0: even slots, 1: odd slots
        const int cp = L & 31;            // column pair (cols 2cp, 2cp+1)
        const bool c3 = (cp < 3);
        for (int n = n0 + w; n <= n1; n += 4) {
            const int os = offs_g[n];
            const int oe = offs_g[n + 1];
            const int s0 = max(os - ebase, 0);
            const int s1 = min(oe - ebase, 256);
            float sx = 0.0f, sy = 0.0f, t3 = 0.0f;
            int slot = s0 + half;
            for (; slot + 2 < s1; slot += 4) {
                const unsigned ua = *(const unsigned*)&A[(slot + 0) * 72 + cp * 2];
                const unsigned ub = *(const unsigned*)&A[(slot + 2) * 72 + cp * 2];
                sx += __uint_as_float(ua << 16) + __uint_as_float(ub << 16);
                sy += __uint_as_float(ua & 0xFFFF0000u) + __uint_as_float(ub & 0xFFFF0000u);
                if (c3) {
                    t3 = fmaf(dif_s[(slot + 0) * 3 + cp], cval_s[slot + 0], t3);
                    t3 = fmaf(dif_s[(slot + 2) * 3 + cp], cval_s[slot + 2], t3);
                }
            }
            if (slot < s1) {
                const unsigned ua = *(const unsigned*)&A[slot * 72 + cp * 2];
                sx += __uint_as_float(ua << 16);
                sy += __uint_as_float(ua & 0xFFFF0000u);
                if (c3) t3 = fmaf(dif_s[slot * 3 + cp], cval_s[slot], t3);
            }
            sx += __shfl_xor(sx, 32, 64);
            sy += __shfl_xor(sy, 32, 64);
            if (c3) t3 += __shfl_xor(t3, 32, 64);
            const bool interior = (os >= ebase) && (oe <= ebase + 256);
            if (half == 0) {
                if (interior) {
                    float2 v; v.x = sx; v.y = sy;
                    *(float2*)&agg[(size_t)n * 64 + cp * 2] = v;
                    if (c3) aggc[n * 3 + cp] = t3;
                } else {
                    atomicAdd(&agg[(size_t)n * 64 + cp * 2 + 0], sx);
                    atomicAdd(&agg[(size_t)n * 64 + cp * 2 + 1], sy);
                    if (c3) atomicAdd(&aggc[n * 3 + cp], t3);
                }
            }
        }
    }
}

// ============================================================================
// k5: node MLP + coord output — 64-node tiles; degree from offs diff
// ============================================================================
__global__ __launch_bounds__(256, 8) void egcl_node_coord(
    const unsigned short* __restrict__ h_bf, const float* __restrict__ agg,
    const float* __restrict__ bn1, const float* __restrict__ bn2,
    const unsigned short* __restrict__ Wtn1, const unsigned short* __restrict__ Wtn2,
    const float* __restrict__ coord, const float* __restrict__ aggc,
    const int* __restrict__ offs,
    float* __restrict__ hout, float* __restrict__ cout)
{
    if (blockIdx.x >= NB5) {
        const int i = (blockIdx.x - NB5) * 256 + threadIdx.x;
        if (i < N_NODES * 3) {
            const int node = i / 3;
            const float c = fmaxf((float)(offs[node + 1] - offs[node]), 1.0f);
            cout[i] = coord[i] + aggc[i] * __builtin_amdgcn_rcpf(c);
        }
        return;
    }

    __shared__ __align__(16) unsigned short A[64 * 136];
    const int t = threadIdx.x;
    const int wave = t >> 6, L = t & 63;
    const int q = L >> 4, lc = L & 15;
    const int nbase = blockIdx.x * 64;
    const int rbase = wave * 16;

    #pragma unroll
    for (int it = 0; it < 8; ++it) {
        const int idx = it * 256 + t;         // 0..2047 = 64 rows x 32 parts
        const int ln = idx >> 5, part = idx & 31;
        const int node = nbase + ln;
        uint2 u;
        if (part < 16) {
            u = *(const uint2*)(h_bf + (size_t)node * 64 + part * 4);
        } else {
            const float4 v = *(const float4*)(agg + (size_t)node * 64 + (part - 16) * 4);
            u = make_uint2(pack_bf2(v.x, v.y), pack_bf2(v.z, v.w));
        }
        *(uint2*)&A[ln * 136 + part * 4] = u;
    }
    __syncthreads();

    f32x4 acc1[4];
    #pragma unroll
    for (int ct = 0; ct < 4; ++ct) {
        const float b = bn1[ct * 16 + lc];
        #pragma unroll
        for (int i = 0; i < 4; ++i) acc1[ct][i] = b;
    }
    #pragma unroll
    for (int ks = 0; ks < 4; ++ks) {
        const bf16x8 af = *(const bf16x8*)&A[(rbase + lc) * 136 + ks * 32 + q * 8];
        #pragma unroll
        for (int ct = 0; ct < 4; ++ct) {
            const bf16x8 bf = *(const bf16x8*)&Wtn1[(ct * 16 + lc) * 128 + ks * 32 + q * 8];
            acc1[ct] = MFMA16(af, bf, acc1[ct]);
        }
    }
    __syncthreads();

    #pragma unroll
    for (int ct = 0; ct < 4; ++ct)
        #pragma unroll
        for (int i = 0; i < 4; ++i) {
            const int row = rbase + q * 4 + i;
            A[row * 72 + ct * 16 + lc] = f2bf(fast_silu(acc1[ct][i]));
        }
    __syncthreads();

    f32x4 acc2[4];
    #pragma unroll
    for (int ct = 0; ct < 4; ++ct) {
        const float b = bn2[ct * 16 + lc];
        #pragma unroll
        for (int i = 0; i < 4; ++i) acc2[ct][i] = b;
    }
    #pragma unroll
    for (int ks = 0; ks < 2; ++ks) {
        const bf16x8 af = *(const bf16x8*)&A[(rbase + lc) * 72 + ks * 32 + q * 8];
        #pragma unroll
        for (int ct = 0; ct < 4; ++ct) {
            const bf16x8 bf = *(const bf16x8*)&Wtn2[(ct * 16 + lc) * 64 + ks * 32 + q * 8];
            acc2[ct] = MFMA16(af, bf, acc2[ct]);
        }
    }

    #pragma unroll
    for (int ct = 0; ct < 4; ++ct)
        #pragma unroll
        for (int i = 0; i < 4; ++i) {
            const int node = nbase + rbase + q * 4 + i;
            hout[(size_t)node * 64 + ct * 16 + lc] = acc2[ct][i];
        }
}

// ============================================================================
// launch
// ============================================================================
extern "C" void kernel_launch(void* const* d_in, const int* in_sizes, int n_in,
                              void* d_out, int out_size, void* d_ws, size_t ws_size,
                              hipStream_t stream)
{
    const float* h     = (const float*)d_in[0];
    const float* coord = (const float*)d_in[1];
    const int*   eidx  = (const int*)d_in[2];
    const float* emask = (const float*)d_in[3];
    const float* We1   = (const float*)d_in[4];
    const float* be1   = (const float*)d_in[5];
    const float* We2   = (const float*)d_in[6];
    const float* be2   = (const float*)d_in[7];
    const float* Wn1   = (const float*)d_in[8];
    const float* bn1   = (const float*)d_in[9];
    const float* Wn2   = (const float*)d_in[10];
    const float* bn2   = (const float*)d_in[11];
    const float* Wc1   = (const float*)d_in[12];
    const float* bc1   = (const float*)d_in[13];
    const float* Wc2   = (const float*)d_in[14];

    float* hout = (float*)d_out;
    float* cout = hout + (size_t)N_NODES * 64;

    // ws layout (all chunks 16B-multiples)
    char* p = (char*)d_ws;
    float* agg  = (float*)p;                      p += (size_t)N_NODES * 64 * 4;   // 10.24 MB
    float* aggc = (float*)p;                      p += (size_t)N_NODES * 3 * 4;    // 0.48 MB (contiguous with agg for zeroing)
    int* hist_x = (int*)p;                        p += (size_t)8 * N_NODES * 4;    // 1.28 MB per-XCD hists
    int* xb     = (int*)p;                        p += (size_t)N_NODES * 8 * 4;    // 1.28 MB xcd prefix
    int* offs   = (int*)p;                        p += (size_t)(N_NODES + 4) * 4;  // 40001 used
    int* cnt    = (int*)p;                        p += (size_t)N_NODES * 4;        // 0.16 MB
    unsigned short* rank = (unsigned short*)p;    p += (size_t)N_EDGES * 2;        // 2.56 MB (u16: xcd<<12 | rank)
    uint2* payload = (uint2*)p;                   p += (size_t)N_EDGES * 8;        // 10.24 MB
    unsigned short* h_bf = (unsigned short*)p;    p += (size_t)N_NODES * 64 * 2;   // 5.12 MB
    float4* coord4 = (float4*)p;                  p += (size_t)N_NODES * 16;       // 0.64 MB
    float* P = (float*)p;                         p += (size_t)N_NODES * 128 * 4;  // 20.48 MB node projections
    unsigned short* Wt2  = (unsigned short*)p;    p += 4096 * 2;
    unsigned short* Wtc1 = (unsigned short*)p;    p += 4096 * 2;
    unsigned short* Wtn1 = (unsigned short*)p;    p += 8192 * 2;
    unsigned short* Wtn2 = (unsigned short*)p;    p += 4096 * 2;

    hipMemsetAsync(hist_x, 0, (size_t)8 * N_NODES * 4, stream);   // 1.28 MB
    hist_rank_kernel<<<K1_GRID, 256, 0, stream>>>(eidx, coord, We2, Wc1, Wn1, Wn2,
                                                  hist_x, rank, coord4,
                                                  Wt2, Wtc1, Wtn1, Wtn2, agg);
    prefix_pgemm_kernel<<<782, 256, 0, stream>>>(hist_x, xb, cnt, h, We1, P);
    scan_kernel<<<1, 1024, 0, stream>>>(cnt, offs);
    scatter_prep_kernel<<<3750, 256, 0, stream>>>(eidx, emask, rank, offs, xb, payload, h, h_bf);
    egcl_edge_mfma<<<N_EDGES / 256, 256, 0, stream>>>(
        P, payload, offs, coord4,
        We1, be1, be2, bc1, Wc2, Wt2, Wtc1, agg, aggc);
    egcl_node_coord<<<NB5 + COORD_BLOCKS, 256, 0, stream>>>(
        h_bf, agg, bn1, bn2, Wtn1, Wtn2, coord, aggc, offs, hout, cout);
}

// Round 11
// 332.696 us; speedup vs baseline: 1.3073x; 1.0297x over previous
//
#include <hip/hip_runtime.h>
#include <stdint.h>

#define N_NODES 40000
#define N_EDGES 1280000
#define HPAD 16               // one hist counter per 64B line

// k1 block-role layout: 1250 atomic blocks striped 1:2 with 2855 streaming blocks
#define K1_GRID 4105          // 1250 hist + 157 coord4 + 80 wpack + 2618 zero
#define NB5 625               // k5: 64-node tiles
#define COORD_BLOCKS 469      // ceil(40000*3/256)

typedef __attribute__((ext_vector_type(8))) short bf16x8;   // 8 bf16 in 4 VGPRs
typedef __attribute__((ext_vector_type(4))) float f32x4;    // MFMA C/D

#define MFMA16(a, b, c) __builtin_amdgcn_mfma_f32_16x16x32_bf16((a), (b), (c), 0, 0, 0)

#if defined(__has_builtin)
#if __has_builtin(__builtin_amdgcn_cvt_pk_bf16_f32)
#define HAS_CVT_PK_BF16 1
#endif
#endif

// ---------- helpers ----------
__device__ __forceinline__ float fast_silu(float x) {
    float e = __expf(-x);
    return x * __builtin_amdgcn_rcpf(1.0f + e);
}

__device__ __forceinline__ unsigned short f2bf(float x) {
    unsigned int u = __float_as_uint(x);
    u = (u + 0x7FFFu + ((u >> 16) & 1u)) >> 16;
    return (unsigned short)u;
}

__device__ __forceinline__ unsigned int pack_bf2(float a, float b) {
#ifdef HAS_CVT_PK_BF16
    typedef __attribute__((ext_vector_type(2))) __bf16 bf2_t;
    bf2_t r = __builtin_amdgcn_cvt_pk_bf16_f32(a, b);   // low = a, high = b, RNE
    return __builtin_bit_cast(unsigned int, r);
#else
    unsigned int ua = __float_as_uint(a);
    unsigned int ub = __float_as_uint(b);
    ua = (ua + 0x7FFFu + ((ua >> 16) & 1u)) >> 16;
    ub = (ub + 0x7FFFu + ((ub >> 16) & 1u)) & 0xFFFF0000u;
    return (ua & 0xFFFFu) | ub;
#endif
}

__device__ __forceinline__ float bf16_to_f(unsigned short s) {
    return __uint_as_float(((unsigned int)s) << 16);
}

// ============================================================================
// k1: hist (padded counters) + u16 rank, striped 1:2 with independent
//     streaming work.
// ============================================================================
__global__ void hist_rank_kernel(const int* __restrict__ eidx, const float* __restrict__ coord,
                                 const float* __restrict__ We2,
                                 const float* __restrict__ Wc1, const float* __restrict__ Wn1,
                                 const float* __restrict__ Wn2,
                                 int* __restrict__ histp, unsigned short* __restrict__ rank,
                                 float4* __restrict__ coord4,
                                 unsigned short* __restrict__ Wt2,
                                 unsigned short* __restrict__ Wtc1, unsigned short* __restrict__ Wtn1,
                                 unsigned short* __restrict__ Wtn2,
                                 float* __restrict__ aggz)
{
    const int g = blockIdx.x;
    if (g < 3750 && (g % 3) == 0) {
        const int i = ((g / 3) * 256 + threadIdx.x) * 4;
        const int4 r = *(const int4*)(eidx + i);
        const int kx = atomicAdd(&histp[r.x * HPAD], 1);
        const int ky = atomicAdd(&histp[r.y * HPAD], 1);
        const int kz = atomicAdd(&histp[r.z * HPAD], 1);
        const int kw = atomicAdd(&histp[r.w * HPAD], 1);
        *(ushort4*)(rank + i) = make_ushort4((unsigned short)kx, (unsigned short)ky,
                                             (unsigned short)kz, (unsigned short)kw);
        return;
    }
    const int s = (g < 3750) ? (g - g / 3 - 1) : (g - 1250);
    if (s < 157) {
        const int n = s * 256 + threadIdx.x;
        if (n < N_NODES)
            coord4[n] = make_float4(coord[n * 3 + 0], coord[n * 3 + 1], coord[n * 3 + 2], 0.f);
    } else if (s < 237) {
        const int t = (s - 157) * 256 + threadIdx.x;
        if (t < 4096)       { Wt2[t]  = f2bf(We2[(t & 63) * 64 + (t >> 6)]); }
        else if (t < 8192)  { int u = t - 4096;  Wtc1[u] = f2bf(Wc1[(u & 63) * 64 + (u >> 6)]); }
        else if (t < 16384) { int u = t - 8192;  Wtn1[u] = f2bf(Wn1[(u & 127) * 64 + (u >> 7)]); }
        else if (t < 20480) { int u = t - 16384; Wtn2[u] = f2bf(Wn2[(u & 63) * 64 + (u >> 6)]); }
    } else {
        const int i = ((s - 237) * 256 + threadIdx.x) * 4;
        if (i < N_NODES * 67)
            *(float4*)(aggz + i) = make_float4(0.f, 0.f, 0.f, 0.f);
    }
}

// ============================================================================
// k2a: compact padded hist -> cnt  PLUS  P-GEMM (P[n] = h[n]@We1 halves, f32)
// ============================================================================
__global__ __launch_bounds__(256) void compact_pgemm_kernel(
    const int* __restrict__ histp, int* __restrict__ cnt,
    const float* __restrict__ h, const float* __restrict__ We1,
    float* __restrict__ P)
{
    const int b = blockIdx.x;
    if (b < 157) {
        const int n = b * 256 + threadIdx.x;
        if (n < N_NODES) cnt[n] = histp[n * HPAD];
        return;
    }
    __shared__ __align__(16) unsigned short Hs[64 * 72];
    __shared__ __align__(16) unsigned short Wa[64 * 72];
    __shared__ __align__(16) unsigned short Wb[64 * 72];
    const int t = threadIdx.x;
    const int nbase = (b - 157) * 64;

    {
        const int nl = t >> 2, seg = t & 3;
        const float* hp = h + (size_t)(nbase + nl) * 64 + seg * 16;
        const float4 v0 = *(const float4*)(hp + 0);
        const float4 v1 = *(const float4*)(hp + 4);
        const float4 v2 = *(const float4*)(hp + 8);
        const float4 v3 = *(const float4*)(hp + 12);
        uint4 a, c;
        a.x = pack_bf2(v0.x, v0.y); a.y = pack_bf2(v0.z, v0.w);
        a.z = pack_bf2(v1.x, v1.y); a.w = pack_bf2(v1.z, v1.w);
        c.x = pack_bf2(v2.x, v2.y); c.y = pack_bf2(v2.z, v2.w);
        c.z = pack_bf2(v3.x, v3.y); c.w = pack_bf2(v3.z, v3.w);
        *(uint4*)&Hs[nl * 72 + seg * 16 + 0] = a;
        *(uint4*)&Hs[nl * 72 + seg * 16 + 8] = c;
    }
    {
        const int out = t >> 2, seg = t & 3;
        unsigned short wa[16], wb[16];
        #pragma unroll
        for (int j = 0; j < 16; ++j) {
            const int k = seg * 16 + j;
            wa[j] = f2bf(We1[k * 64 + out]);
            wb[j] = f2bf(We1[(64 + k) * 64 + out]);
        }
        *(uint4*)&Wa[out * 72 + seg * 16 + 0] = *(const uint4*)&wa[0];
        *(uint4*)&Wa[out * 72 + seg * 16 + 8] = *(const uint4*)&wa[8];
        *(uint4*)&Wb[out * 72 + seg * 16 + 0] = *(const uint4*)&wb[0];
        *(uint4*)&Wb[out * 72 + seg * 16 + 8] = *(const uint4*)&wb[8];
    }
    __syncthreads();

    const int wave = t >> 6, L = t & 63;
    const int q = L >> 4, lc = L & 15;
    const int wbase = wave * 16;

    f32x4 acc[4][2];
    #pragma unroll
    for (int ot = 0; ot < 4; ++ot)
        #pragma unroll
        for (int hf = 0; hf < 2; ++hf)
            #pragma unroll
            for (int i = 0; i < 4; ++i) acc[ot][hf][i] = 0.0f;

    #pragma unroll
    for (int ks = 0; ks < 2; ++ks) {
        const bf16x8 bfr = *(const bf16x8*)&Hs[(wbase + lc) * 72 + ks * 32 + q * 8];
        #pragma unroll
        for (int ot = 0; ot < 4; ++ot) {
            const bf16x8 afa = *(const bf16x8*)&Wa[(ot * 16 + lc) * 72 + ks * 32 + q * 8];
            acc[ot][0] = MFMA16(afa, bfr, acc[ot][0]);
            const bf16x8 afb = *(const bf16x8*)&Wb[(ot * 16 + lc) * 72 + ks * 32 + q * 8];
            acc[ot][1] = MFMA16(afb, bfr, acc[ot][1]);
        }
    }
    float* pr = P + (size_t)(nbase + wbase + lc) * 128;
    #pragma unroll
    for (int ot = 0; ot < 4; ++ot) {
        *(f32x4*)(pr + ot * 16 + q * 4)      = acc[ot][0];
        *(f32x4*)(pr + 64 + ot * 16 + q * 4) = acc[ot][1];
    }
}

// ============================================================================
// k2b: single-block scan; offs[0..N_NODES] inclusive sentinel
// ============================================================================
__global__ __launch_bounds__(1024) void scan_kernel(const int* __restrict__ cnt,
                                                    int* __restrict__ offs) {
    __shared__ int wtot[16];
    __shared__ int carry_s;
    const int t = threadIdx.x;
    const int wave = t >> 6, lane = t & 63;
    if (t == 0) carry_s = 0;
    __syncthreads();
    for (int base = 0; base < N_NODES; base += 8192) {
        const int idx = base + t * 8;
        int v[8];
        if (idx + 8 <= N_NODES) {
            const int4 a = *(const int4*)(cnt + idx);
            const int4 b = *(const int4*)(cnt + idx + 4);
            v[0] = a.x; v[1] = a.y; v[2] = a.z; v[3] = a.w;
            v[4] = b.x; v[5] = b.y; v[6] = b.z; v[7] = b.w;
        } else {
            #pragma unroll
            for (int j = 0; j < 8; ++j) v[j] = (idx + j < N_NODES) ? cnt[idx + j] : 0;
        }
        int s = 0;
        #pragma unroll
        for (int j = 0; j < 8; ++j) s += v[j];
        int S = s;
        #pragma unroll
        for (int d = 1; d < 64; d <<= 1) {
            const int u = __shfl_up(S, d, 64);
            if (lane >= d) S += u;
        }
        if (lane == 63) wtot[wave] = S;
        __syncthreads();
        if (wave == 0 && lane < 16) {
            int w = wtot[lane];
            #pragma unroll
            for (int d = 1; d < 16; d <<= 1) {
                const int u = __shfl_up(w, d, 64);
                if (lane >= d) w += u;
            }
            wtot[lane] = w;
        }
        __syncthreads();
        const int wb = (wave == 0) ? 0 : wtot[wave - 1];
        int run = carry_s + wb + (S - s);
        #pragma unroll
        for (int j = 0; j < 8; ++j) {
            if (idx + j < N_NODES) offs[idx + j] = run;
            run += v[j];
        }
        __syncthreads();
        if (t == 0) carry_s += wtot[15];
        __syncthreads();
    }
    if (t == 0) offs[N_NODES] = N_EDGES;
}

// ============================================================================
// k3: scatter 8B payloads (rc, mask) via offs[r]+rank[e] (NO atomics) + h pack.
// ============================================================================
__global__ void scatter_prep_kernel(const int* __restrict__ eidx, const float* __restrict__ emask,
                                    const unsigned short* __restrict__ rank,
                                    const int* __restrict__ offs,
                                    uint2* __restrict__ payload,
                                    const float* __restrict__ h,
                                    unsigned short* __restrict__ h_bf)
{
    const int b = blockIdx.x;
    if (b < 1250) {
        const int i = (b * 256 + threadIdx.x) * 4;
        const int4 r = *(const int4*)(eidx + i);
        const int4 c = *(const int4*)(eidx + N_EDGES + i);
        const float4 mk = *(const float4*)(emask + i);
        const ushort4 k = *(const ushort4*)(rank + i);
        #pragma unroll
        for (int j = 0; j < 4; ++j) {
            const int rj = (&r.x)[j], cj = (&c.x)[j];
            const int slot = offs[rj] + (int)(&k.x)[j];
            payload[slot] = make_uint2((unsigned)rj | ((unsigned)cj << 16),
                                       __float_as_uint((&mk.x)[j]));
        }
    } else {
        const int i = ((b - 1250) * 256 + threadIdx.x) * 4;   // exactly covers 2,560,000
        const float4 v = *(const float4*)(h + i);
        *(uint2*)(h_bf + i) = make_uint2(pack_bf2(v.x, v.y), pack_bf2(v.z, v.w));
    }
}

// ============================================================================
// k4: edge kernel. Layer1 replaced by per-node P-table gathers:
//     m1 = silu(P[row][0:64] + P[col][64:128] + rad*w + b).
//     (R6 winner verbatim — 140.5 us, MfmaUtil 6.2, not BW-bound.)
// ============================================================================
__global__ __launch_bounds__(256, 4) void egcl_edge_mfma(
    const float* __restrict__ P,
    const uint2* __restrict__ payload,
    const int* __restrict__ offs_g,
    const float4* __restrict__ coord4,
    const float* __restrict__ We1, const float* __restrict__ be1,
    const float* __restrict__ be2, const float* __restrict__ bc1,
    const float* __restrict__ Wc2,
    const unsigned short* __restrict__ Wt2,
    const unsigned short* __restrict__ Wtc1,
    float* __restrict__ agg, float* __restrict__ aggc)
{
    __shared__ __align__(16) unsigned short A[256 * 72];
    __shared__ float dif_s[768];
    __shared__ float cval_s[256];

    const int t = threadIdx.x;
    const int w = t >> 6, L = t & 63;
    const int q = L >> 4, lc = L & 15;
    const int ebase = blockIdx.x * 256;
    const int rbase = w * 64;

    // ---- meta: 8B coalesced payload + 2 L2-resident coord4 gathers ----
    int my_r, my_c;
    float my_rad, my_msk;
    {
        const uint2 pl = payload[ebase + t];
        my_r = (int)(pl.x & 0xFFFFu);
        my_c = (int)(pl.x >> 16);
        my_msk = __uint_as_float(pl.y);
        const float4 cr = coord4[my_r];
        const float4 cc = coord4[my_c];
        const float d0 = cr.x - cc.x, d1 = cr.y - cc.y, d2 = cr.z - cc.z;
        my_rad = d0 * d0 + d1 * d1 + d2 * d2;
        dif_s[t * 3 + 0] = d0; dif_s[t * 3 + 1] = d1; dif_s[t * 3 + 2] = d2;
        if (t == 0)   *(int*)&A[64] = my_r;   // n0 in row-0 padding
        if (t == 255) *(int*)&A[66] = my_r;   // n1
    }

    // per-et indices / rad / mask via shfl (slot et*16+lc is in this wave)
    int r_et[4], c_et[4];
    float rad_et[4], mk_et[4];
    #pragma unroll
    for (int et = 0; et < 4; ++et) {
        r_et[et]   = __shfl(my_r, et * 16 + lc, 64);
        c_et[et]   = __shfl(my_c, et * 16 + lc, 64);
        rad_et[et] = __shfl(my_rad, et * 16 + lc, 64);
        mk_et[et]  = __shfl(my_msk, et * 16 + lc, 64);
    }

    // ---- layer1 = bias + rad*w + P[row] + P[col] (f32, no MFMA) ----
    f32x4 acc[4][4];   // [ot][et]
    #pragma unroll
    for (int ot = 0; ot < 4; ++ot) {
        const float4 bv = *(const float4*)(be1 + ot * 16 + q * 4);
        const float4 wv = *(const float4*)(We1 + 128 * 64 + ot * 16 + q * 4);
        #pragma unroll
        for (int et = 0; et < 4; ++et) {
            const float rad = rad_et[et];
            acc[ot][et][0] = fmaf(rad, wv.x, bv.x);
            acc[ot][et][1] = fmaf(rad, wv.y, bv.y);
            acc[ot][et][2] = fmaf(rad, wv.z, bv.z);
            acc[ot][et][3] = fmaf(rad, wv.w, bv.w);
        }
    }
    #pragma unroll
    for (int et = 0; et < 4; ++et) {
        const float* p1 = P + (size_t)r_et[et] * 128;
        const float* p2 = P + (size_t)c_et[et] * 128 + 64;
        #pragma unroll
        for (int ot = 0; ot < 4; ++ot) {
            const f32x4 a = *(const f32x4*)(p1 + ot * 16 + q * 4);
            const f32x4 b = *(const f32x4*)(p2 + ot * 16 + q * 4);
            acc[ot][et][0] += a[0] + b[0];
            acc[ot][et][1] += a[1] + b[1];
            acc[ot][et][2] += a[2] + b[2];
            acc[ot][et][3] += a[3] + b[3];
        }
    }

    // ---- m1 = silu -> A ----
    #pragma unroll
    for (int et = 0; et < 4; ++et) {
        const int row = rbase + et * 16 + lc;
        #pragma unroll
        for (int ot = 0; ot < 4; ++ot) {
            uint2 p;
            p.x = pack_bf2(fast_silu(acc[ot][et][0]), fast_silu(acc[ot][et][1]));
            p.y = pack_bf2(fast_silu(acc[ot][et][2]), fast_silu(acc[ot][et][3]));
            *(uint2*)&A[row * 72 + ot * 16 + q * 4] = p;
        }
    }

    // ---- layer2 ----
    f32x4 acc2[4][4];
    #pragma unroll
    for (int ot = 0; ot < 4; ++ot) {
        const float4 bv = *(const float4*)(be2 + ot * 16 + q * 4);
        #pragma unroll
        for (int et = 0; et < 4; ++et) {
            acc2[ot][et][0] = bv.x; acc2[ot][et][1] = bv.y;
            acc2[ot][et][2] = bv.z; acc2[ot][et][3] = bv.w;
        }
    }
    #pragma unroll
    for (int ks = 0; ks < 2; ++ks) {
        bf16x8 bfr[4];
        #pragma unroll
        for (int et = 0; et < 4; ++et)
            bfr[et] = *(const bf16x8*)&A[(rbase + et * 16 + lc) * 72 + ks * 32 + q * 8];
        #pragma unroll
        for (int ot = 0; ot < 4; ++ot) {
            const bf16x8 af = *(const bf16x8*)&Wt2[(ot * 16 + lc) * 64 + ks * 32 + q * 8];
            #pragma unroll
            for (int et = 0; et < 4; ++et)
                acc2[ot][et] = MFMA16(af, bfr[et], acc2[ot][et]);
        }
    }

    // ---- m = silu * mask -> A ----
    #pragma unroll
    for (int et = 0; et < 4; ++et) {
        const int row = rbase + et * 16 + lc;
        const float mk = mk_et[et];
        #pragma unroll
        for (int ot = 0; ot < 4; ++ot) {
            uint2 p;
            p.x = pack_bf2(fast_silu(acc2[ot][et][0]) * mk, fast_silu(acc2[ot][et][1]) * mk);
            p.y = pack_bf2(fast_silu(acc2[ot][et][2]) * mk, fast_silu(acc2[ot][et][3]) * mk);
            *(uint2*)&A[row * 72 + ot * 16 + q * 4] = p;
        }
    }

    // ---- coord mlp ----
    f32x4 acc3[4][4];
    #pragma unroll
    for (int ot = 0; ot < 4; ++ot) {
        const float4 bv = *(const float4*)(bc1 + ot * 16 + q * 4);
        #pragma unroll
        for (int et = 0; et < 4; ++et) {
            acc3[ot][et][0] = bv.x; acc3[ot][et][1] = bv.y;
            acc3[ot][et][2] = bv.z; acc3[ot][et][3] = bv.w;
        }
    }
    #pragma unroll
    for (int ks = 0; ks < 2; ++ks) {
        bf16x8 bfr[4];
        #pragma unroll
        for (int et = 0; et < 4; ++et)
            bfr[et] = *(const bf16x8*)&A[(rbase + et * 16 + lc) * 72 + ks * 32 + q * 8];
        #pragma unroll
        for (int ot = 0; ot < 4; ++ot) {
            const bf16x8 af = *(const bf16x8*)&Wtc1[(ot * 16 + lc) * 64 + ks * 32 + q * 8];
            #pragma unroll
            for (int et = 0; et < 4; ++et)
                acc3[ot][et] = MFMA16(af, bfr[et], acc3[ot][et]);
        }
    }
    {
        float4 wv[4];
        #pragma unroll
        for (int ot = 0; ot < 4; ++ot) wv[ot] = *(const float4*)(Wc2 + ot * 16 + q * 4);
        #pragma unroll
        for (int et = 0; et < 4; ++et) {
            float s = 0.0f;
            #pragma unroll
            for (int ot = 0; ot < 4; ++ot) {
                s = fmaf(fast_silu(acc3[ot][et][0]), wv[ot].x, s);
                s = fmaf(fast_silu(acc3[ot][et][1]), wv[ot].y, s);
                s = fmaf(fast_silu(acc3[ot][et][2]), wv[ot].z, s);
                s = fmaf(fast_silu(acc3[ot][et][3]), wv[ot].w, s);
            }
            s += __shfl_xor(s, 16, 64);
            s += __shfl_xor(s, 32, 64);
            if (q == 0)
                cval_s[rbase + et * 16 + lc] = s * mk_et[et];
        }
    }

    __syncthreads();   // whole block's m / cval / dif now valid

    // ---- fused segmented aggregation: lane-halves over even/odd slots,
    //      b32 (2-column) LDS reads, shfl_xor(32) combine, float2 stores ----
    {
        const int n0 = *(const int*)&A[64];
        const int n1 = *(const int*)&A[66];
        const int half = L >> 5;          // 0: even slots, 1: odd slots
        const int cp = L & 31;            // column pair (cols 2cp, 2cp+1)
        const bool c3 = (cp < 3);
        for (int n = n0 + w; n <= n1; n += 4) {
            const int os = offs_g[n];
            const int oe = offs_g[n + 1];
            const int s0 = max(os - ebase, 0);
            const int s1 = min(oe - ebase, 256);
            float sx = 0.0f, sy = 0.0f, t3 = 0.0f;
            int slot = s0 + half;
            for (; slot + 2 < s1; slot += 4) {
                const unsigned ua = *(const unsigned*)&A[(slot + 0) * 72 + cp * 2];
                const unsigned ub = *(const unsigned*)&A[(slot + 2) * 72 + cp * 2];
                sx += __uint_as_float(ua << 16) + __uint_as_float(ub << 16);
                sy += __uint_as_float(ua & 0xFFFF0000u) + __uint_as_float(ub & 0xFFFF0000u);
                if (c3) {
                    t3 = fmaf(dif_s[(slot + 0) * 3 + cp], cval_s[slot + 0], t3);
                    t3 = fmaf(dif_s[(slot + 2) * 3 + cp], cval_s[slot + 2], t3);
                }
            }
            if (slot < s1) {
                const unsigned ua = *(const unsigned*)&A[slot * 72 + cp * 2];
                sx += __uint_as_float(ua << 16);
                sy += __uint_as_float(ua & 0xFFFF0000u);
                if (c3) t3 = fmaf(dif_s[slot * 3 + cp], cval_s[slot], t3);
            }
            sx += __shfl_xor(sx, 32, 64);
            sy += __shfl_xor(sy, 32, 64);
            if (c3) t3 += __shfl_xor(t3, 32, 64);
            const bool interior = (os >= ebase) && (oe <= ebase + 256);
            if (half == 0) {
                if (interior) {
                    float2 v; v.x = sx; v.y = sy;
                    *(float2*)&agg[(size_t)n * 64 + cp * 2] = v;
                    if (c3) aggc[n * 3 + cp] = t3;
                } else {
                    atomicAdd(&agg[(size_t)n * 64 + cp * 2 + 0], sx);
                    atomicAdd(&agg[(size_t)n * 64 + cp * 2 + 1], sy);
                    if (c3) atomicAdd(&aggc[n * 3 + cp], t3);
                }
            }
        }
    }
}

// ============================================================================
// k5: node MLP + coord output — 64-node tiles; degree from offs diff
// ============================================================================
__global__ __launch_bounds__(256, 8) void egcl_node_coord(
    const unsigned short* __restrict__ h_bf, const float* __restrict__ agg,
    const float* __restrict__ bn1, const float* __restrict__ bn2,
    const unsigned short* __restrict__ Wtn1, const unsigned short* __restrict__ Wtn2,
    const float* __restrict__ coord, const float* __restrict__ aggc,
    const int* __restrict__ offs,
    float* __restrict__ hout, float* __restrict__ cout)
{
    if (blockIdx.x >= NB5) {
        const int i = (blockIdx.x - NB5) * 256 + threadIdx.x;
        if (i < N_NODES * 3) {
            const int node = i / 3;
            const float c = fmaxf((float)(offs[node + 1] - offs[node]), 1.0f);
            cout[i] = coord[i] + aggc[i] * __builtin_amdgcn_rcpf(c);
        }
        return;
    }

    __shared__ __align__(16) unsigned short A[64 * 136];
    const int t = threadIdx.x;
    const int wave = t >> 6, L = t & 63;
    const int q = L >> 4, lc = L & 15;
    const int nbase = blockIdx.x * 64;
    const int rbase = wave * 16;

    #pragma unroll
    for (int it = 0; it < 8; ++it) {
        const int idx = it * 256 + t;         // 0..2047 = 64 rows x 32 parts
        const int ln = idx >> 5, part = idx & 31;
        const int node = nbase + ln;
        uint2 u;
        if (part < 16) {
            u = *(const uint2*)(h_bf + (size_t)node * 64 + part * 4);
        } else {
            const float4 v = *(const float4*)(agg + (size_t)node * 64 + (part - 16) * 4);
            u = make_uint2(pack_bf2(v.x, v.y), pack_bf2(v.z, v.w));
        }
        *(uint2*)&A[ln * 136 + part * 4] = u;
    }
    __syncthreads();

    f32x4 acc1[4];
    #pragma unroll
    for (int ct = 0; ct < 4; ++ct) {
        const float b = bn1[ct * 16 + lc];
        #pragma unroll
        for (int i = 0; i < 4; ++i) acc1[ct][i] = b;
    }
    #pragma unroll
    for (int ks = 0; ks < 4; ++ks) {
        const bf16x8 af = *(const bf16x8*)&A[(rbase + lc) * 136 + ks * 32 + q * 8];
        #pragma unroll
        for (int ct = 0; ct < 4; ++ct) {
            const bf16x8 bf = *(const bf16x8*)&Wtn1[(ct * 16 + lc) * 128 + ks * 32 + q * 8];
            acc1[ct] = MFMA16(af, bf, acc1[ct]);
        }
    }
    __syncthreads();

    #pragma unroll
    for (int ct = 0; ct < 4; ++ct)
        #pragma unroll
        for (int i = 0; i < 4; ++i) {
            const int row = rbase + q * 4 + i;
            A[row * 72 + ct * 16 + lc] = f2bf(fast_silu(acc1[ct][i]));
        }
    __syncthreads();

    f32x4 acc2[4];
    #pragma unroll
    for (int ct = 0; ct < 4; ++ct) {
        const float b = bn2[ct * 16 + lc];
        #pragma unroll
        for (int i = 0; i < 4; ++i) acc2[ct][i] = b;
    }
    #pragma unroll
    for (int ks = 0; ks < 2; ++ks) {
        const bf16x8 af = *(const bf16x8*)&A[(rbase + lc) * 72 + ks * 32 + q * 8];
        #pragma unroll
        for (int ct = 0; ct < 4; ++ct) {
            const bf16x8 bf = *(const bf16x8*)&Wtn2[(ct * 16 + lc) * 64 + ks * 32 + q * 8];
            acc2[ct] = MFMA16(af, bf, acc2[ct]);
        }
    }

    #pragma unroll
    for (int ct = 0; ct < 4; ++ct)
        #pragma unroll
        for (int i = 0; i < 4; ++i) {
            const int node = nbase + rbase + q * 4 + i;
            hout[(size_t)node * 64 + ct * 16 + lc] = acc2[ct][i];
        }
}

// ============================================================================
// launch
// ============================================================================
extern "C" void kernel_launch(void* const* d_in, const int* in_sizes, int n_in,
                              void* d_out, int out_size, void* d_ws, size_t ws_size,
                              hipStream_t stream)
{
    const float* h     = (const float*)d_in[0];
    const float* coord = (const float*)d_in[1];
    const int*   eidx  = (const int*)d_in[2];
    const float* emask = (const float*)d_in[3];
    const float* We1   = (const float*)d_in[4];
    const float* be1   = (const float*)d_in[5];
    const float* We2   = (const float*)d_in[6];
    const float* be2   = (const float*)d_in[7];
    const float* Wn1   = (const float*)d_in[8];
    const float* bn1   = (const float*)d_in[9];
    const float* Wn2   = (const float*)d_in[10];
    const float* bn2   = (const float*)d_in[11];
    const float* Wc1   = (const float*)d_in[12];
    const float* bc1   = (const float*)d_in[13];
    const float* Wc2   = (const float*)d_in[14];

    float* hout = (float*)d_out;
    float* cout = hout + (size_t)N_NODES * 64;

    // ws layout (all chunks 16B-multiples)
    char* p = (char*)d_ws;
    float* agg  = (float*)p;                      p += (size_t)N_NODES * 64 * 4;   // 10.24 MB
    float* aggc = (float*)p;                      p += (size_t)N_NODES * 3 * 4;    // 0.48 MB (contiguous with agg for zeroing)
    int* histp  = (int*)p;                        p += (size_t)N_NODES * HPAD * 4; // 2.56 MB padded hist
    int* offs   = (int*)p;                        p += (size_t)(N_NODES + 4) * 4;  // 40001 used
    int* cnt    = (int*)p;                        p += (size_t)N_NODES * 4;        // 0.16 MB
    unsigned short* rank = (unsigned short*)p;    p += (size_t)N_EDGES * 2;        // 2.56 MB (u16)
    uint2* payload = (uint2*)p;                   p += (size_t)N_EDGES * 8;        // 10.24 MB
    unsigned short* h_bf = (unsigned short*)p;    p += (size_t)N_NODES * 64 * 2;   // 5.12 MB
    float4* coord4 = (float4*)p;                  p += (size_t)N_NODES * 16;       // 0.64 MB
    float* P = (float*)p;                         p += (size_t)N_NODES * 128 * 4;  // 20.48 MB node projections
    unsigned short* Wt2  = (unsigned short*)p;    p += 4096 * 2;
    unsigned short* Wtc1 = (unsigned short*)p;    p += 4096 * 2;
    unsigned short* Wtn1 = (unsigned short*)p;    p += 8192 * 2;
    unsigned short* Wtn2 = (unsigned short*)p;    p += 4096 * 2;

    hipMemsetAsync(histp, 0, (size_t)N_NODES * HPAD * 4, stream);   // 2.56 MB
    hist_rank_kernel<<<K1_GRID, 256, 0, stream>>>(eidx, coord, We2, Wc1, Wn1, Wn2,
                                                  histp, rank, coord4,
                                                  Wt2, Wtc1, Wtn1, Wtn2, agg);
    compact_pgemm_kernel<<<782, 256, 0, stream>>>(histp, cnt, h, We1, P);
    scan_kernel<<<1, 1024, 0, stream>>>(cnt, offs);
    scatter_prep_kernel<<<3750, 256, 0, stream>>>(eidx, emask, rank, offs, payload, h, h_bf);
    egcl_edge_mfma<<<N_EDGES / 256, 256, 0, stream>>>(
        P, payload, offs, coord4,
        We1, be1, be2, bc1, Wc2, Wt2, Wtc1, agg, aggc);
    egcl_node_coord<<<NB5 + COORD_BLOCKS, 256, 0, stream>>>(
        h_bf, agg, bn1, bn2, Wtn1, Wtn2, coord, aggc, offs, hout, cout);
}